// Round 4
// baseline (1751.448 us; speedup 1.0000x reference)
//
#include <hip/hip_runtime.h>

typedef __attribute__((ext_vector_type(4))) float f32x4;
typedef __attribute__((ext_vector_type(8))) short bf16x8;
typedef unsigned short u16;

#define DEVINL static __device__ __forceinline__

DEVINL float b2f(u16 u) { union { unsigned int i; float f; } x; x.i = ((unsigned int)u) << 16; return x.f; }
DEVINL u16 f2bf(float f) {
  union { float f; unsigned int i; } x; x.f = f;
  unsigned int r = x.i + 0x7fffu + ((x.i >> 16) & 1u);
  return (u16)(r >> 16);
}
DEVINL float ldin(const void* p, long i, int f) {
  return f ? ((const float*)p)[i] : b2f(((const u16*)p)[i]);
}
DEVINL void ld4bf(const u16* p, float* o) {
  ushort4 v = *(const ushort4*)p;
  o[0] = b2f(v.x); o[1] = b2f(v.y); o[2] = b2f(v.z); o[3] = b2f(v.w);
}
DEVINL void st4out(void* out, size_t idx, const float* v, int f) {
  if (f) {
    float4 t; t.x = v[0]; t.y = v[1]; t.z = v[2]; t.w = v[3];
    *(float4*)((float*)out + idx) = t;
  } else {
    ushort4 t; t.x = f2bf(v[0]); t.y = f2bf(v[1]); t.z = f2bf(v[2]); t.w = f2bf(v[3]);
    *(ushort4*)((u16*)out + idx) = t;
  }
}

// ---------------- workspace layout (bytes) ----------------
static constexpr size_t OFF_FLAG = 0;
static constexpr size_t OFF_WIH  = 1024;        // bf16 [8][1536][448]
static constexpr size_t OFF_QVW  = 11011072;    // bf16 [8][768][512]  (qc 0:128 | kc 128:256 | vc 256:768)
static constexpr size_t OFF_OUTW = 23593984;    // bf16 [8][512][448]
static constexpr size_t OFF_VALW = 27264000;    // bf16 [512][512]
static constexpr size_t OFF_WHH  = 27788288;    // bf16 [8][1536][512]
static constexpr size_t OFF_VBP  = 40371200;    // bf16 [512]
static constexpr size_t OFF_BIH  = 40372224;    // bf16 [8][1536]
static constexpr size_t OFF_BHH  = 40396800;    // bf16 [8][1536]
static constexpr size_t OFF_RNG  = 40421376;    // bf16 [8][512]
static constexpr size_t OFF_RNB  = 40429568;    // bf16 [8][512]
static constexpr size_t OFF_LNG  = 40437760;    // bf16 [512]
static constexpr size_t OFF_LNB  = 40438784;    // bf16 [512]
static constexpr size_t OFF_HMF  = 40439808;    // f32  [4096]
static constexpr size_t OFF_XB   = 40456192;    // bf16 [4096][512]
static constexpr size_t OFF_HSB  = 44650496;    // bf16 [8][4096][512] (u-major)
static constexpr size_t OFF_KL   = 78204928;    // f32  [4096][64]
static constexpr size_t OFF_VL   = 79253504;    // f32  [4096][512]
static constexpr size_t OFF_QL   = 87642112;    // f32  [4096][512]  (=[b][u*64+n])
static constexpr size_t OFF_MASK = 96030720;    // f32  [4096][8]
static constexpr size_t OFF_HB   = 96161792;    // bf16 [8][4096][512]
static constexpr size_t OFF_R    = 129716224;   // reusable region
static constexpr size_t OFF_INP  = OFF_R;                 // bf16 [8][4096][448]
static constexpr size_t OFF_GI   = OFF_R + 29360128;      // bf16 [8][1024][1536] (chunk)
static constexpr size_t OFF_GH   = OFF_R + 54525952;      // bf16 [8][1024][1536] (chunk)
static constexpr size_t OFF_QVC  = OFF_R;                 // bf16 [8][2048][768]  (chunk)
static constexpr size_t OFF_CTX  = OFF_R + 25165824;      // bf16 [8][2048][448]  (chunk)
static constexpr size_t OFF_CTX2 = OFF_R + 39845888;      // bf16 [8][2048][512]  (chunk)
// peak = 209,408,000 bytes

// ---------------- dtype detect v2: even-u16 plausibility ----------------
// bf16 buffer: even u16s are bf16 normals (~100% in [2^-40,2^40]).
// fp32 buffer: even u16s are low mantissa bits -> log-uniform exponent (~31%).
__global__ __launch_bounds__(256) void detect_kernel(const u16* __restrict__ hs_u, int* __restrict__ flag) {
  __shared__ int cnt;
  if (threadIdx.x == 0) cnt = 0;
  __syncthreads();
  int ok = 0;
  for (int i = threadIdx.x; i < 1024; i += 256) {
    const float v = fabsf(b2f(hs_u[2 * i]));
    if (v > 9.094947e-13f && v < 1.0995116e12f) ok++;   // 2^-40 .. 2^40
  }
  atomicAdd(&cnt, ok);
  __syncthreads();
  if (threadIdx.x == 0) flag[0] = (cnt >= 921) ? 0 : 1;  // >=90% plausible -> bf16(0) else fp32(1)
}

// ---------------- prep + convert everything to canonical bf16 ----------------
__global__ __launch_bounds__(256) void prepconv_kernel(
    const void* __restrict__ W_ih, const void* __restrict__ qc_w, const void* __restrict__ kc_w,
    const void* __restrict__ vc_w, const void* __restrict__ out_w, const void* __restrict__ value_w,
    const void* __restrict__ value_b, const void* __restrict__ W_hh, const void* __restrict__ b_ih,
    const void* __restrict__ b_hh, const void* __restrict__ rnn_g, const void* __restrict__ rnn_b,
    const void* __restrict__ ln_g, const void* __restrict__ ln_b, const void* __restrict__ x,
    const void* __restrict__ hs, const void* __restrict__ h_masks, const int* __restrict__ flagp,
    u16* __restrict__ WIH, u16* __restrict__ QVW, u16* __restrict__ OUTW, u16* __restrict__ VALW,
    u16* __restrict__ WHH, u16* __restrict__ VBP, u16* __restrict__ BIH, u16* __restrict__ BHH,
    u16* __restrict__ RNG, u16* __restrict__ RNB, u16* __restrict__ LNG, u16* __restrict__ LNB,
    u16* __restrict__ XB, u16* __restrict__ HSB, float* __restrict__ HMF)
{
  const int f = flagp[0];
  long i = (long)blockIdx.x * 256 + threadIdx.x;
  if (i < 5505024L) {                       // WIH [u*1536=r][448], pad k>=400
    long r = i / 448; int k = (int)(i - r * 448);
    WIH[i] = (k < 400) ? f2bf(ldin(W_ih, r * 400 + k, f)) : (u16)0;
    return;
  }
  i -= 5505024L;
  if (i < 3145728L) {                       // QVW [u][768][512]
    int u = (int)(i / 393216); long j = i - (long)u * 393216;
    int n = (int)(j >> 9), k = (int)(j & 511);
    float v;
    if (n < 128)      v = ldin(qc_w, ((long)u * 512 + k) * 128 + n, f);
    else if (n < 256) v = ldin(kc_w, ((long)u * 512 + k) * 128 + (n - 128), f);
    else { int m = n - 256; v = (m < 400) ? ldin(vc_w, ((long)u * 512 + k) * 400 + m, f) : 0.f; }
    QVW[i] = f2bf(v);
    return;
  }
  i -= 3145728L;
  if (i < 1835008L) {                       // OUTW [u][512][448], pad k>=400
    long t = i / 448; int k = (int)(i - t * 448); int n = (int)(t & 511); int u = (int)(t >> 9);
    OUTW[i] = (k < 400) ? f2bf(ldin(out_w, ((long)u * 400 + k) * 512 + n, f)) : (u16)0;
    return;
  }
  i -= 1835008L;
  if (i < 262144L) {                        // VALW [512][512], pad n>=400
    int n = (int)(i >> 9), k = (int)(i & 511);
    VALW[i] = (n < 400) ? f2bf(ldin(value_w, (long)k * 400 + n, f)) : (u16)0;
    return;
  }
  i -= 262144L;
  if (i < 6291456L) { WHH[i] = f2bf(ldin(W_hh, i, f)); return; }
  i -= 6291456L;
  if (i < 512L) { VBP[i] = (i < 400) ? f2bf(ldin(value_b, i, f)) : (u16)0; return; }
  i -= 512L;
  if (i < 12288L) { BIH[i] = f2bf(ldin(b_ih, i, f)); return; }
  i -= 12288L;
  if (i < 12288L) { BHH[i] = f2bf(ldin(b_hh, i, f)); return; }
  i -= 12288L;
  if (i < 4096L) { RNG[i] = f2bf(ldin(rnn_g, i, f)); return; }
  i -= 4096L;
  if (i < 4096L) { RNB[i] = f2bf(ldin(rnn_b, i, f)); return; }
  i -= 4096L;
  if (i < 512L) { LNG[i] = f2bf(ldin(ln_g, i, f)); return; }
  i -= 512L;
  if (i < 512L) { LNB[i] = f2bf(ldin(ln_b, i, f)); return; }
  i -= 512L;
  if (i < 2097152L) { XB[i] = f2bf(ldin(x, i, f)); return; }
  i -= 2097152L;
  if (i < 16777216L) {                      // HSB [u][b][h] <- hs[b][u][h]
    long u = i >> 21, rem = i & 2097151L, b = rem >> 9; int h = (int)(rem & 511);
    HSB[i] = f2bf(ldin(hs, (b * 8 + u) * 512 + h, f));
    return;
  }
  i -= 16777216L;
  if (i < 4096L) { HMF[i] = ldin(h_masks, i, f); return; }
}

// ---------------- SIMPLE fp32-accum NT GEMM (bisect reference path, out0) ----------------
template<int OUT_BF16, int HAS_BIAS>
__global__ __launch_bounds__(256) void gemm_nt_simple_kernel(
    const u16* __restrict__ A, const u16* __restrict__ W, void* __restrict__ Cp,
    const u16* __restrict__ bias, int KP, long Az, long Wz, long Cz, int Bz, int ldc)
{
  __shared__ float sA[16][68];
  __shared__ float sW[16][68];
  const int tid = threadIdx.x;
  const int m0 = blockIdx.x * 64, n0 = blockIdx.y * 64, z = blockIdx.z;
  const u16* Au = A + (size_t)z * Az;
  const u16* Wu = W + (size_t)z * Wz;
  const int tx = tid & 15, ty = tid >> 4;
  const int r = tid >> 2, q = (tid & 3) * 4;
  float acc[4][4] = {};
  for (int k0 = 0; k0 < KP; k0 += 16) {
    __syncthreads();
    const ushort4 av = *(const ushort4*)(Au + (size_t)(m0 + r) * KP + k0 + q);
    const ushort4 wv = *(const ushort4*)(Wu + (size_t)(n0 + r) * KP + k0 + q);
    sA[q + 0][r] = b2f(av.x); sA[q + 1][r] = b2f(av.y);
    sA[q + 2][r] = b2f(av.z); sA[q + 3][r] = b2f(av.w);
    sW[q + 0][r] = b2f(wv.x); sW[q + 1][r] = b2f(wv.y);
    sW[q + 2][r] = b2f(wv.z); sW[q + 3][r] = b2f(wv.w);
    __syncthreads();
#pragma unroll
    for (int kk = 0; kk < 16; ++kk) {
      const float a0 = sA[kk][ty * 4 + 0], a1 = sA[kk][ty * 4 + 1];
      const float a2 = sA[kk][ty * 4 + 2], a3 = sA[kk][ty * 4 + 3];
      const float b0 = sW[kk][tx * 4 + 0], b1 = sW[kk][tx * 4 + 1];
      const float b2 = sW[kk][tx * 4 + 2], b3 = sW[kk][tx * 4 + 3];
      acc[0][0] += a0 * b0; acc[0][1] += a0 * b1; acc[0][2] += a0 * b2; acc[0][3] += a0 * b3;
      acc[1][0] += a1 * b0; acc[1][1] += a1 * b1; acc[1][2] += a1 * b2; acc[1][3] += a1 * b3;
      acc[2][0] += a2 * b0; acc[2][1] += a2 * b1; acc[2][2] += a2 * b2; acc[2][3] += a2 * b3;
      acc[3][0] += a3 * b0; acc[3][1] += a3 * b1; acc[3][2] += a3 * b2; acc[3][3] += a3 * b3;
    }
  }
  float* Cf = (float*)Cp;
  u16* Cb = (u16*)Cp;
#pragma unroll
  for (int i = 0; i < 4; ++i)
#pragma unroll
    for (int j = 0; j < 4; ++j) {
      const int gr = m0 + ty * 4 + i, gc = n0 + tx * 4 + j;
      float v = acc[i][j];
      if (HAS_BIAS) v += b2f(bias[(size_t)z * Bz + gc]);
      const size_t idx = (size_t)z * Cz + (size_t)gr * ldc + gc;
      if (OUT_BF16) Cb[idx] = f2bf(v); else Cf[idx] = v;
    }
}

// ---------------- bf16 MFMA NT GEMM (out1 path, bisect probe) ----------------
template<int OUT_BF16, int HAS_BIAS>
__global__ __launch_bounds__(256) void gemm_bt_kernel(
    const u16* __restrict__ A, const u16* __restrict__ W, void* __restrict__ Cp,
    const u16* __restrict__ bias, int KP, long Az, long Wz, long Cz, int Bz, int ldc)
{
  __shared__ u16 lA[128 * 64];
  __shared__ u16 lB[128 * 64];
  const int tid = threadIdx.x;
  const int m0 = blockIdx.x * 128, n0 = blockIdx.y * 128, z = blockIdx.z;
  const u16* Au = A + (size_t)z * Az;
  const u16* Wu = W + (size_t)z * Wz;

  const int l = tid & 63, w = tid >> 6;
  const int WM = (w >> 1) * 64, WN = (w & 1) * 64;
  const int lr = l & 15, kg = l >> 4;

  f32x4 acc[4][4];
#pragma unroll
  for (int i = 0; i < 4; ++i)
#pragma unroll
    for (int j = 0; j < 4; ++j) acc[i][j] = (f32x4){0.f, 0.f, 0.f, 0.f};

  const int rowA = tid >> 3;
  const int cb = (tid & 7) * 16;
  const size_t rowBytes = (size_t)KP * 2;

  for (int k0 = 0; k0 < KP; k0 += 64) {
    __syncthreads();
    const char* gA = (const char*)Au + (size_t)(m0 + rowA) * rowBytes + (size_t)k0 * 2 + cb;
    const char* gB = (const char*)Wu + (size_t)(n0 + rowA) * rowBytes + (size_t)k0 * 2 + cb;
    char* sA = (char*)lA + (w << 10);
    char* sB = (char*)lB + (w << 10);
#pragma unroll
    for (int c = 0; c < 4; ++c) {
      __builtin_amdgcn_global_load_lds(
          (const __attribute__((address_space(1))) void*)(gA + (size_t)c * 32 * rowBytes),
          (__attribute__((address_space(3))) void*)(sA + c * 4096), 16, 0, 0);
      __builtin_amdgcn_global_load_lds(
          (const __attribute__((address_space(1))) void*)(gB + (size_t)c * 32 * rowBytes),
          (__attribute__((address_space(3))) void*)(sB + c * 4096), 16, 0, 0);
    }
    __syncthreads();
#pragma unroll
    for (int kk = 0; kk < 64; kk += 32) {
      bf16x8 af[4], bw[4];
#pragma unroll
      for (int i = 0; i < 4; ++i)
        af[i] = *(const bf16x8*)&lA[(WM + i * 16 + lr) * 64 + kk + kg * 8];
#pragma unroll
      for (int j = 0; j < 4; ++j)
        bw[j] = *(const bf16x8*)&lB[(WN + j * 16 + lr) * 64 + kk + kg * 8];
#pragma unroll
      for (int i = 0; i < 4; ++i)
#pragma unroll
        for (int j = 0; j < 4; ++j)
          acc[i][j] = __builtin_amdgcn_mfma_f32_16x16x32_bf16(af[i], bw[j], acc[i][j], 0, 0, 0);
    }
  }
  float* Cf = (float*)Cp;
  u16* Cb = (u16*)Cp;
#pragma unroll
  for (int i = 0; i < 4; ++i) {
#pragma unroll
    for (int j = 0; j < 4; ++j) {
      const int gc = n0 + WN + j * 16 + lr;
      float bv = 0.f;
      if (HAS_BIAS) bv = b2f(bias[(size_t)z * Bz + gc]);
#pragma unroll
      for (int t = 0; t < 4; ++t) {
        const int gr = m0 + WM + i * 16 + kg * 4 + t;
        const float v = acc[i][j][t] + bv;
        const size_t idx = (size_t)z * Cz + (size_t)gr * ldc + gc;
        if (OUT_BF16) Cb[idx] = f2bf(v); else Cf[idx] = v;
      }
    }
  }
}

// ---------------- exact-dtype fp32 GEMM for the score path ----------------
__global__ __launch_bounds__(256) void gemm_f32bf_kernel(
    const void* __restrict__ A, const void* __restrict__ W, float* __restrict__ C,
    const void* __restrict__ bias, const int* __restrict__ flagp,
    int K, int lda, int ldw, int ldc, long Az, long Wz, long Cz)
{
  const int f32 = flagp[0];
  __shared__ float sA[16][65];
  __shared__ float sW[16][64];
  const int tid = threadIdx.x;
  const int m0 = blockIdx.x * 64, n0 = blockIdx.y * 64, z = blockIdx.z;
  const int tx = tid & 15, ty = tid >> 4;
  const int ar = tid >> 2, ak = (tid & 3) * 4;
  const int wk = tid >> 4, wc = (tid & 15) * 4;
  const size_t abase = (size_t)z * Az, wbase = (size_t)z * Wz;
  float acc[4][4] = {};
  for (int k0 = 0; k0 < K; k0 += 16) {
    __syncthreads();
    float a0, a1, a2, a3, w0, w1, w2, w3;
    const size_t ai = abase + (size_t)(m0 + ar) * lda + k0 + ak;
    const size_t wi = wbase + (size_t)(k0 + wk) * ldw + n0 + wc;
    if (f32) {
      const float4 av = *(const float4*)((const float*)A + ai);
      const float4 wv = *(const float4*)((const float*)W + wi);
      a0 = av.x; a1 = av.y; a2 = av.z; a3 = av.w;
      w0 = wv.x; w1 = wv.y; w2 = wv.z; w3 = wv.w;
    } else {
      const ushort4 av = *(const ushort4*)((const u16*)A + ai);
      const ushort4 wv = *(const ushort4*)((const u16*)W + wi);
      a0 = b2f(av.x); a1 = b2f(av.y); a2 = b2f(av.z); a3 = b2f(av.w);
      w0 = b2f(wv.x); w1 = b2f(wv.y); w2 = b2f(wv.z); w3 = b2f(wv.w);
    }
    sA[ak + 0][ar] = a0; sA[ak + 1][ar] = a1; sA[ak + 2][ar] = a2; sA[ak + 3][ar] = a3;
    sW[wk][wc] = w0; sW[wk][wc + 1] = w1; sW[wk][wc + 2] = w2; sW[wk][wc + 3] = w3;
    __syncthreads();
#pragma unroll
    for (int kk = 0; kk < 16; ++kk) {
      const float a0c = sA[kk][ty * 4 + 0], a1c = sA[kk][ty * 4 + 1];
      const float a2c = sA[kk][ty * 4 + 2], a3c = sA[kk][ty * 4 + 3];
      const float4 bv = *(const float4*)&sW[kk][tx * 4];
      acc[0][0] += a0c * bv.x; acc[0][1] += a0c * bv.y; acc[0][2] += a0c * bv.z; acc[0][3] += a0c * bv.w;
      acc[1][0] += a1c * bv.x; acc[1][1] += a1c * bv.y; acc[1][2] += a1c * bv.z; acc[1][3] += a1c * bv.w;
      acc[2][0] += a2c * bv.x; acc[2][1] += a2c * bv.y; acc[2][2] += a2c * bv.z; acc[2][3] += a2c * bv.w;
      acc[3][0] += a3c * bv.x; acc[3][1] += a3c * bv.y; acc[3][2] += a3c * bv.z; acc[3][3] += a3c * bv.w;
    }
  }
#pragma unroll
  for (int i = 0; i < 4; ++i)
#pragma unroll
    for (int j = 0; j < 4; ++j) {
      const int n = n0 + tx * 4 + j;
      float v = acc[i][j];
      if (bias) v += ldin(bias, n, f32);
      C[(size_t)z * Cz + (size_t)(m0 + ty * 4 + i) * ldc + n] = v;
    }
}

// ---------------- scores / top-k / probs -> mask, inp ----------------
__global__ __launch_bounds__(256) void select_kernel(
    const float* __restrict__ q_l, const float* __restrict__ k_l,
    const void* __restrict__ key_b, const void* __restrict__ value_b,
    const float* __restrict__ v_l, const int* __restrict__ flagp,
    float* __restrict__ mask_out, u16* __restrict__ inp)
{
  const int b = blockIdx.x, tid = threadIdx.x;
  const int f32 = flagp[0];
  __shared__ float s_sc[16], s_pm[8], s_pm1[8];
  __shared__ float s_v[400], s_vb[400];
  const int task = tid >> 4, l16 = tid & 15, uu = task & 7;
  const float* qv = q_l + (size_t)b * 512 + uu * 64;
  float p = 0.f;
  if (task < 8) {
    const float* kv = k_l + (size_t)b * 64;
    for (int k = l16; k < 64; k += 16) p += qv[k] * kv[k];
  } else {
    for (int k = l16; k < 64; k += 16) p += qv[k] * ldin(key_b, k, f32);
  }
  p += __shfl_xor(p, 8, 16); p += __shfl_xor(p, 4, 16);
  p += __shfl_xor(p, 2, 16); p += __shfl_xor(p, 1, 16);
  if (l16 == 0) s_sc[task] = p * 0.125f;
  for (int i = tid; i < 400; i += 256) { s_v[i] = v_l[(size_t)b * 512 + i]; s_vb[i] = ldin(value_b, i, f32); }
  __syncthreads();
  if (tid < 8) {
    const float s0 = s_sc[tid];
    int rank = 0;
    for (int u2 = 0; u2 < 8; ++u2) {
      const float o = s_sc[u2];
      rank += (o > s0) || (o == s0 && u2 < tid);
    }
    const float m = (rank < 5) ? 1.f : 0.f;
    mask_out[(size_t)b * 8 + tid] = m;
    const float s1 = s_sc[8 + tid];
    const float mx = fmaxf(s0, s1);
    const float e0 = expf(s0 - mx), e1 = expf(s1 - mx);
    const float p0 = e0 / (e0 + e1);
    s_pm[tid] = m * p0; s_pm1[tid] = m * (1.f - p0);
  }
  __syncthreads();
#pragma unroll
  for (int u = 0; u < 8; ++u) {
    const float pm = s_pm[u], pm1 = s_pm1[u];
    for (int i = tid; i < 448; i += 256) {
      const float v = (i < 400) ? (pm * s_v[i] + pm1 * s_vb[i]) : 0.f;
      inp[((size_t)u * 4096 + b) * 448 + i] = f2bf(v);
    }
  }
}

// ---------------- shared 2-value block reduction (128 threads) ----------------
__device__ __forceinline__ void block_reduce_2(float& a, float& b) {
#pragma unroll
  for (int o = 32; o; o >>= 1) { a += __shfl_down(a, o, 64); b += __shfl_down(b, o, 64); }
  __shared__ float red[4];
  const int tid = threadIdx.x;
  if ((tid & 63) == 0) { red[(tid >> 6) * 2] = a; red[(tid >> 6) * 2 + 1] = b; }
  __syncthreads();
  a = red[0] + red[2]; b = red[1] + red[3];
}

// ---------------- GRU gates (hmask+b_hh fold) + per-unit LN -> out0, hb ----------------
__global__ __launch_bounds__(128) void gates_kernel(
    const u16* __restrict__ gi, const u16* __restrict__ gh,
    const u16* __restrict__ hsb, const float* __restrict__ hmf,
    const u16* __restrict__ bhh, const u16* __restrict__ rng, const u16* __restrict__ rnb,
    const int* __restrict__ flagp, int bbase, void* __restrict__ out0, u16* __restrict__ hb)
{
  const int f = flagp[0];
  const int bid = blockIdx.x;
  const int u = bid >> 10, bl = bid & 1023;
  const int b = bbase + bl;
  const int h0 = threadIdx.x * 4;
  const size_t rowg = ((size_t)u * 1024 + bl) * 1536;
  const size_t rowh = ((size_t)u * 4096 + b) * 512;
  float ir[4], iz[4], inn[4], hr[4], hz[4], hnn[4], hsv[4], br[4], bz[4], bn[4];
  ld4bf(gi + rowg + h0, ir);
  ld4bf(gi + rowg + 512 + h0, iz);
  ld4bf(gi + rowg + 1024 + h0, inn);
  ld4bf(gh + rowg + h0, hr);
  ld4bf(gh + rowg + 512 + h0, hz);
  ld4bf(gh + rowg + 1024 + h0, hnn);
  ld4bf(hsb + rowh + h0, hsv);
  ld4bf(bhh + u * 1536 + h0, br);
  ld4bf(bhh + u * 1536 + 512 + h0, bz);
  ld4bf(bhh + u * 1536 + 1024 + h0, bn);
  const float hmask = hmf[b];
  float hn[4]; float sum = 0.f, sq = 0.f;
#pragma unroll
  for (int j = 0; j < 4; ++j) {
    const float hrf = hmask * hr[j] + br[j];
    const float hzf = hmask * hz[j] + bz[j];
    const float hnf = hmask * hnn[j] + bn[j];
    const float r = 1.f / (1.f + expf(-(ir[j] + hrf)));
    const float zz = 1.f / (1.f + expf(-(iz[j] + hzf)));
    const float n = tanhf(inn[j] + r * hnf);
    const float hmv = hsv[j] * hmask;
    const float h = (1.f - zz) * n + zz * hmv;
    hn[j] = h; sum += h; sq += h * h;
  }
  block_reduce_2(sum, sq);
  const float mean = sum * (1.f / 512.f);
  const float var = fmaxf(sq * (1.f / 512.f) - mean * mean, 0.f);
  const float rstd = rsqrtf(var + 1e-5f);
  float gg[4], bb[4];
  ld4bf(rng + u * 512 + h0, gg);
  ld4bf(rnb + u * 512 + h0, bb);
  float yv[4];
#pragma unroll
  for (int j = 0; j < 4; ++j) yv[j] = (hn[j] - mean) * rstd * gg[j] + bb[j];
  st4out(out0, (size_t)b * 4096 + u * 512 + h0, yv, f);
  ushort4 hv;
  hv.x = f2bf(hn[0]); hv.y = f2bf(hn[1]); hv.z = f2bf(hn[2]); hv.w = f2bf(hn[3]);
  *(ushort4*)(hb + rowh + h0) = hv;
}

// ---------------- per-b 8x8 inter-unit attention -> ctx ----------------
__global__ __launch_bounds__(256) void attn_kernel(
    const u16* __restrict__ qvc, const float* __restrict__ maskp, int bbase,
    u16* __restrict__ ctx)
{
  const int bl = blockIdx.x, tid = threadIdx.x;
  const int b = bbase + bl;
  __shared__ float s_q[8][128], s_k[8][128];
  __shared__ float s_ap[4][8][8];
  __shared__ float s_v[8][400];
  for (int i = tid; i < 1024; i += 256) {
    const int u = i >> 7, c = i & 127;
    const size_t base = ((size_t)u * 2048 + bl) * 768;
    s_q[u][c] = b2f(qvc[base + c]);
    s_k[u][c] = b2f(qvc[base + 128 + c]);
  }
  for (int i = tid; i < 3200; i += 256) {
    const int u = i / 400, c = i - u * 400;
    s_v[u][c] = b2f(qvc[((size_t)u * 2048 + bl) * 768 + 256 + c]);
  }
  __syncthreads();
  const int n = tid >> 6, uu = (tid >> 3) & 7, vv = tid & 7;
  float a = 0.f;
#pragma unroll
  for (int k = 0; k < 32; ++k) a += s_q[uu][n * 32 + k] * s_k[vv][n * 32 + k];
  a *= 0.17677669529663687f;
  float mx = a;
  for (int o = 4; o; o >>= 1) mx = fmaxf(mx, __shfl_xor(mx, o, 8));
  const float e = expf(a - mx);
  float se = e;
  for (int o = 4; o; o >>= 1) se += __shfl_xor(se, o, 8);
  s_ap[n][uu][vv] = e / se * maskp[(size_t)b * 8 + uu];
  __syncthreads();
  for (int i = tid; i < 3584; i += 256) {
    const int u = i / 448, c = i - u * 448;
    float v = 0.f;
    if (c < 400) {
      const int nn = c / 100;
      const float* ap = s_ap[nn][u];
#pragma unroll
      for (int v2 = 0; v2 < 8; ++v2) v += ap[v2] * s_v[v2][c];
    }
    ctx[((size_t)u * 2048 + bl) * 448 + c] = f2bf(v);
  }
}

// ---------------- final LN + masked blend -> out2 ----------------
__global__ __launch_bounds__(128) void final_kernel(
    const u16* __restrict__ ctx2, const u16* __restrict__ hb, const u16* __restrict__ hsb,
    const float* __restrict__ maskp, const u16* __restrict__ lng, const u16* __restrict__ lnb,
    const int* __restrict__ flagp, int bbase, void* __restrict__ outp)
{
  const int f = flagp[0];
  const int bid = blockIdx.x;
  const int u = bid >> 11, bl = bid & 2047;
  const int b = bbase + bl;
  const int h0 = threadIdx.x * 4;
  const size_t rowc = ((size_t)u * 2048 + bl) * 512;
  const size_t rowh = ((size_t)u * 4096 + b) * 512;
  float cv[4], hbv[4];
  ld4bf(ctx2 + rowc + h0, cv);
  ld4bf(hb + rowh + h0, hbv);
  float v[4] = { cv[0] + hbv[0], cv[1] + hbv[1], cv[2] + hbv[2], cv[3] + hbv[3] };
  float sum = v[0] + v[1] + v[2] + v[3];
  float sq = v[0] * v[0] + v[1] * v[1] + v[2] * v[2] + v[3] * v[3];
  block_reduce_2(sum, sq);
  const float mean = sum * (1.f / 512.f);
  const float var = fmaxf(sq * (1.f / 512.f) - mean * mean, 0.f);
  const float rstd = rsqrtf(var + 1e-5f);
  float gg[4], bb2[4], hsv[4];
  ld4bf(lng + h0, gg); ld4bf(lnb + h0, bb2); ld4bf(hsb + rowh + h0, hsv);
  const float msk = maskp[(size_t)b * 8 + u];
  float ov[4];
#pragma unroll
  for (int j = 0; j < 4; ++j)
    ov[j] = msk * ((v[j] - mean) * rstd * gg[j] + bb2[j]) + (1.f - msk) * hsv[j];
  st4out(outp, (size_t)16777216 + (size_t)(b * 8 + u) * 512 + h0, ov, f);
}

extern "C" void kernel_launch(void* const* d_in, const int* in_sizes, int n_in,
                              void* d_out, int out_size, void* d_ws, size_t ws_size,
                              hipStream_t stream) {
  const void* x       = d_in[0];
  const void* hs      = d_in[1];
  const void* h_masks = d_in[2];
  const void* key_w   = d_in[3];
  const void* key_b   = d_in[4];
  const void* value_w = d_in[5];
  const void* value_b = d_in[6];
  const void* query_w = d_in[7];
  const void* qc_w    = d_in[8];
  const void* kc_w    = d_in[9];
  const void* vc_w    = d_in[10];
  const void* out_w   = d_in[11];
  const void* ln_g    = d_in[12];
  const void* ln_b    = d_in[13];
  const void* W_ih    = d_in[14];
  const void* b_ih    = d_in[15];
  const void* W_hh    = d_in[16];
  const void* b_hh    = d_in[17];
  const void* rnn_g   = d_in[18];
  const void* rnn_b   = d_in[19];

  char* ws = (char*)d_ws;
  int*   FLAG = (int*)(ws + OFF_FLAG);
  u16*   WIH  = (u16*)(ws + OFF_WIH);
  u16*   QVW  = (u16*)(ws + OFF_QVW);
  u16*   OUTW = (u16*)(ws + OFF_OUTW);
  u16*   VALW = (u16*)(ws + OFF_VALW);
  u16*   WHH  = (u16*)(ws + OFF_WHH);
  u16*   VBP  = (u16*)(ws + OFF_VBP);
  u16*   BIH  = (u16*)(ws + OFF_BIH);
  u16*   BHH  = (u16*)(ws + OFF_BHH);
  u16*   RNG  = (u16*)(ws + OFF_RNG);
  u16*   RNB  = (u16*)(ws + OFF_RNB);
  u16*   LNG  = (u16*)(ws + OFF_LNG);
  u16*   LNB  = (u16*)(ws + OFF_LNB);
  float* HMF  = (float*)(ws + OFF_HMF);
  u16*   XB   = (u16*)(ws + OFF_XB);
  u16*   HSB  = (u16*)(ws + OFF_HSB);
  float* KL   = (float*)(ws + OFF_KL);
  float* VL   = (float*)(ws + OFF_VL);
  float* QL   = (float*)(ws + OFF_QL);
  float* MASK = (float*)(ws + OFF_MASK);
  u16*   HB   = (u16*)(ws + OFF_HB);
  u16*   INP  = (u16*)(ws + OFF_INP);
  u16*   GI   = (u16*)(ws + OFF_GI);
  u16*   GH   = (u16*)(ws + OFF_GH);
  u16*   QVC  = (u16*)(ws + OFF_QVC);
  u16*   CTX  = (u16*)(ws + OFF_CTX);
  u16*   CTX2 = (u16*)(ws + OFF_CTX2);

  detect_kernel<<<1, 256, 0, stream>>>((const u16*)hs, FLAG);
  prepconv_kernel<<<140438, 256, 0, stream>>>(
      W_ih, qc_w, kc_w, vc_w, out_w, value_w, value_b, W_hh, b_ih, b_hh,
      rnn_g, rnn_b, ln_g, ln_b, x, hs, h_masks, FLAG,
      WIH, QVW, OUTW, VALW, WHH, VBP, BIH, BHH, RNG, RNB, LNG, LNB, XB, HSB, HMF);
  // --- output-0 path: SIMPLE GEMM (bisect) ---
  gemm_nt_simple_kernel<0, 1><<<dim3(64, 8, 1), 256, 0, stream>>>(XB, VALW, VL, VBP, 512, 0, 0, 0, 0, 512);
  gemm_f32bf_kernel<<<dim3(64, 1, 1), 256, 0, stream>>>(x, key_w, KL, key_b, FLAG, 512, 512, 64, 64, 0, 0, 0);
  gemm_f32bf_kernel<<<dim3(64, 1, 8), 256, 0, stream>>>(hs, query_w, QL, nullptr, FLAG, 512, 4096, 64, 512, 512, 32768, 64);
  select_kernel<<<4096, 256, 0, stream>>>(QL, KL, key_b, value_b, VL, FLAG, MASK, INP);
  for (int c = 0; c < 4; ++c) {
    gemm_nt_simple_kernel<1, 1><<<dim3(16, 24, 8), 256, 0, stream>>>(
        INP + (size_t)c * 1024 * 448, WIH, GI, BIH, 448, 1835008L, 688128L, 1572864L, 1536, 1536);
    gemm_nt_simple_kernel<1, 0><<<dim3(16, 24, 8), 256, 0, stream>>>(
        HSB + (size_t)c * 1024 * 512, WHH, GH, nullptr, 512, 2097152L, 786432L, 1572864L, 0, 1536);
    gates_kernel<<<8192, 128, 0, stream>>>(GI, GH, HSB, HMF, BHH, RNG, RNB, FLAG, c * 1024, d_out, HB);
  }
  // --- output-1 path: MFMA (bisect probe) ---
  for (int d = 0; d < 2; ++d) {
    gemm_bt_kernel<1, 0><<<dim3(16, 6, 8), 256, 0, stream>>>(
        HB + (size_t)d * 2048 * 512, QVW, QVC, nullptr, 512, 2097152L, 393216L, 1572864L, 0, 768);
    attn_kernel<<<2048, 256, 0, stream>>>(QVC, MASK, d * 2048, CTX);
    gemm_bt_kernel<1, 0><<<dim3(16, 4, 8), 256, 0, stream>>>(
        CTX, OUTW, CTX2, nullptr, 448, 917504L, 229376L, 1048576L, 0, 512);
    final_kernel<<<16384, 128, 0, stream>>>(CTX2, HB, HSB, MASK, LNG, LNB, FLAG, d * 2048, d_out);
  }
  (void)in_sizes; (void)n_in; (void)out_size; (void)ws_size;
}

// Round 5
// 703.688 us; speedup vs baseline: 2.4890x; 2.4890x over previous
//
#include <hip/hip_runtime.h>

typedef __attribute__((ext_vector_type(4))) float f32x4;
typedef __attribute__((ext_vector_type(8))) short bf16x8;
typedef unsigned short u16;

#define DEVINL static __device__ __forceinline__

DEVINL float b2f(u16 u) { union { unsigned int i; float f; } x; x.i = ((unsigned int)u) << 16; return x.f; }
DEVINL u16 f2bf(float f) {
  union { float f; unsigned int i; } x; x.f = f;
  unsigned int r = x.i + 0x7fffu + ((x.i >> 16) & 1u);
  return (u16)(r >> 16);
}
DEVINL float ldin(const void* p, long i, int f) {
  return f ? ((const float*)p)[i] : b2f(((const u16*)p)[i]);
}
DEVINL void ld4bf(const u16* p, float* o) {
  ushort4 v = *(const ushort4*)p;
  o[0] = b2f(v.x); o[1] = b2f(v.y); o[2] = b2f(v.z); o[3] = b2f(v.w);
}
DEVINL void st4out(void* out, size_t idx, const float* v, int f) {
  if (f) {
    float4 t; t.x = v[0]; t.y = v[1]; t.z = v[2]; t.w = v[3];
    *(float4*)((float*)out + idx) = t;
  } else {
    ushort4 t; t.x = f2bf(v[0]); t.y = f2bf(v[1]); t.z = f2bf(v[2]); t.w = f2bf(v[3]);
    *(ushort4*)((u16*)out + idx) = t;
  }
}

// ---------------- workspace layout (bytes) ----------------
static constexpr size_t OFF_FLAG = 0;
static constexpr size_t OFF_WIH  = 1024;        // bf16 [8][1536][448]
static constexpr size_t OFF_QVW  = 11011072;    // bf16 [8][768][512]  (qc 0:128 | kc 128:256 | vc 256:768)
static constexpr size_t OFF_OUTW = 23593984;    // bf16 [8][512][448]
static constexpr size_t OFF_VALW = 27264000;    // bf16 [512][512]
static constexpr size_t OFF_WHH  = 27788288;    // bf16 [8][1536][512]
static constexpr size_t OFF_VBP  = 40371200;    // bf16 [512]
static constexpr size_t OFF_BIH  = 40372224;    // bf16 [8][1536]
static constexpr size_t OFF_BHH  = 40396800;    // bf16 [8][1536]
static constexpr size_t OFF_RNG  = 40421376;    // bf16 [8][512]
static constexpr size_t OFF_RNB  = 40429568;    // bf16 [8][512]
static constexpr size_t OFF_LNG  = 40437760;    // bf16 [512]
static constexpr size_t OFF_LNB  = 40438784;    // bf16 [512]
static constexpr size_t OFF_HMF  = 40439808;    // f32  [4096]
static constexpr size_t OFF_XB   = 40456192;    // bf16 [4096][512]
static constexpr size_t OFF_HSB  = 44650496;    // bf16 [8][4096][512] (u-major)
static constexpr size_t OFF_KL   = 78204928;    // f32  [4096][64]
static constexpr size_t OFF_VL   = 79253504;    // f32  [4096][512]
static constexpr size_t OFF_QL   = 87642112;    // f32  [4096][512]  (=[b][u*64+n])
static constexpr size_t OFF_MASK = 96030720;    // f32  [4096][8]
static constexpr size_t OFF_HB   = 96161792;    // bf16 [8][4096][512]
static constexpr size_t OFF_R    = 129716224;   // reusable region
static constexpr size_t OFF_INP  = OFF_R;                 // bf16 [8][4096][448]
static constexpr size_t OFF_GI   = OFF_R + 29360128;      // bf16 [8][1024][1536] (chunk)
static constexpr size_t OFF_GH   = OFF_R + 54525952;      // bf16 [8][1024][1536] (chunk)
static constexpr size_t OFF_QVC  = OFF_R;                 // bf16 [8][2048][768]  (chunk)
static constexpr size_t OFF_CTX  = OFF_R + 25165824;      // bf16 [8][2048][448]  (chunk)
static constexpr size_t OFF_CTX2 = OFF_R + 39845888;      // bf16 [8][2048][512]  (chunk)
// peak = 209,408,000 bytes

// ---------------- dtype detect: even-u16 plausibility ----------------
__global__ __launch_bounds__(256) void detect_kernel(const u16* __restrict__ hs_u, int* __restrict__ flag) {
  __shared__ int cnt;
  if (threadIdx.x == 0) cnt = 0;
  __syncthreads();
  int ok = 0;
  for (int i = threadIdx.x; i < 1024; i += 256) {
    const float v = fabsf(b2f(hs_u[2 * i]));
    if (v > 9.094947e-13f && v < 1.0995116e12f) ok++;   // 2^-40 .. 2^40
  }
  atomicAdd(&cnt, ok);
  __syncthreads();
  if (threadIdx.x == 0) flag[0] = (cnt >= 921) ? 0 : 1;  // >=90% plausible -> bf16(0) else fp32(1)
}

// ---------------- prep + convert everything to canonical bf16 ----------------
__global__ __launch_bounds__(256) void prepconv_kernel(
    const void* __restrict__ W_ih, const void* __restrict__ qc_w, const void* __restrict__ kc_w,
    const void* __restrict__ vc_w, const void* __restrict__ out_w, const void* __restrict__ value_w,
    const void* __restrict__ value_b, const void* __restrict__ W_hh, const void* __restrict__ b_ih,
    const void* __restrict__ b_hh, const void* __restrict__ rnn_g, const void* __restrict__ rnn_b,
    const void* __restrict__ ln_g, const void* __restrict__ ln_b, const void* __restrict__ x,
    const void* __restrict__ hs, const void* __restrict__ h_masks, const int* __restrict__ flagp,
    u16* __restrict__ WIH, u16* __restrict__ QVW, u16* __restrict__ OUTW, u16* __restrict__ VALW,
    u16* __restrict__ WHH, u16* __restrict__ VBP, u16* __restrict__ BIH, u16* __restrict__ BHH,
    u16* __restrict__ RNG, u16* __restrict__ RNB, u16* __restrict__ LNG, u16* __restrict__ LNB,
    u16* __restrict__ XB, u16* __restrict__ HSB, float* __restrict__ HMF)
{
  const int f = flagp[0];
  long i = (long)blockIdx.x * 256 + threadIdx.x;
  if (i < 5505024L) {                       // WIH [u*1536=r][448], pad k>=400
    long r = i / 448; int k = (int)(i - r * 448);
    WIH[i] = (k < 400) ? f2bf(ldin(W_ih, r * 400 + k, f)) : (u16)0;
    return;
  }
  i -= 5505024L;
  if (i < 3145728L) {                       // QVW [u][768][512]
    int u = (int)(i / 393216); long j = i - (long)u * 393216;
    int n = (int)(j >> 9), k = (int)(j & 511);
    float v;
    if (n < 128)      v = ldin(qc_w, ((long)u * 512 + k) * 128 + n, f);
    else if (n < 256) v = ldin(kc_w, ((long)u * 512 + k) * 128 + (n - 128), f);
    else { int m = n - 256; v = (m < 400) ? ldin(vc_w, ((long)u * 512 + k) * 400 + m, f) : 0.f; }
    QVW[i] = f2bf(v);
    return;
  }
  i -= 3145728L;
  if (i < 1835008L) {                       // OUTW [u][512][448], pad k>=400
    long t = i / 448; int k = (int)(i - t * 448); int n = (int)(t & 511); int u = (int)(t >> 9);
    OUTW[i] = (k < 400) ? f2bf(ldin(out_w, ((long)u * 400 + k) * 512 + n, f)) : (u16)0;
    return;
  }
  i -= 1835008L;
  if (i < 262144L) {                        // VALW [512][512], pad n>=400
    int n = (int)(i >> 9), k = (int)(i & 511);
    VALW[i] = (n < 400) ? f2bf(ldin(value_w, (long)k * 400 + n, f)) : (u16)0;
    return;
  }
  i -= 262144L;
  if (i < 6291456L) { WHH[i] = f2bf(ldin(W_hh, i, f)); return; }
  i -= 6291456L;
  if (i < 512L) { VBP[i] = (i < 400) ? f2bf(ldin(value_b, i, f)) : (u16)0; return; }
  i -= 512L;
  if (i < 12288L) { BIH[i] = f2bf(ldin(b_ih, i, f)); return; }
  i -= 12288L;
  if (i < 12288L) { BHH[i] = f2bf(ldin(b_hh, i, f)); return; }
  i -= 12288L;
  if (i < 4096L) { RNG[i] = f2bf(ldin(rnn_g, i, f)); return; }
  i -= 4096L;
  if (i < 4096L) { RNB[i] = f2bf(ldin(rnn_b, i, f)); return; }
  i -= 4096L;
  if (i < 512L) { LNG[i] = f2bf(ldin(ln_g, i, f)); return; }
  i -= 512L;
  if (i < 512L) { LNB[i] = f2bf(ldin(ln_b, i, f)); return; }
  i -= 512L;
  if (i < 2097152L) { XB[i] = f2bf(ldin(x, i, f)); return; }
  i -= 2097152L;
  if (i < 16777216L) {                      // HSB [u][b][h] <- hs[b][u][h]
    long u = i >> 21, rem = i & 2097151L, b = rem >> 9; int h = (int)(rem & 511);
    HSB[i] = f2bf(ldin(hs, (b * 8 + u) * 512 + h, f));
    return;
  }
  i -= 16777216L;
  if (i < 4096L) { HMF[i] = ldin(h_masks, i, f); return; }
}

// ---------------- bf16 MFMA NT GEMM: C[M][ldc] = A[M][KP] @ W[N][KP]^T (+bias) ----------------
// Verified correct (round 3/4 bisect: out1 path passed through this kernel).
template<int OUT_BF16, int HAS_BIAS>
__global__ __launch_bounds__(256) void gemm_bt_kernel(
    const u16* __restrict__ A, const u16* __restrict__ W, void* __restrict__ Cp,
    const u16* __restrict__ bias, int KP, long Az, long Wz, long Cz, int Bz, int ldc)
{
  __shared__ u16 lA[128 * 64];
  __shared__ u16 lB[128 * 64];
  const int tid = threadIdx.x;
  const int m0 = blockIdx.x * 128, n0 = blockIdx.y * 128, z = blockIdx.z;
  const u16* Au = A + (size_t)z * Az;
  const u16* Wu = W + (size_t)z * Wz;

  const int l = tid & 63, w = tid >> 6;
  const int WM = (w >> 1) * 64, WN = (w & 1) * 64;
  const int lr = l & 15, kg = l >> 4;

  f32x4 acc[4][4];
#pragma unroll
  for (int i = 0; i < 4; ++i)
#pragma unroll
    for (int j = 0; j < 4; ++j) acc[i][j] = (f32x4){0.f, 0.f, 0.f, 0.f};

  const int rowA = tid >> 3;
  const int cb = (tid & 7) * 16;
  const size_t rowBytes = (size_t)KP * 2;

  for (int k0 = 0; k0 < KP; k0 += 64) {
    __syncthreads();
    const char* gA = (const char*)Au + (size_t)(m0 + rowA) * rowBytes + (size_t)k0 * 2 + cb;
    const char* gB = (const char*)Wu + (size_t)(n0 + rowA) * rowBytes + (size_t)k0 * 2 + cb;
    char* sA = (char*)lA + (w << 10);
    char* sB = (char*)lB + (w << 10);
#pragma unroll
    for (int c = 0; c < 4; ++c) {
      __builtin_amdgcn_global_load_lds(
          (const __attribute__((address_space(1))) void*)(gA + (size_t)c * 32 * rowBytes),
          (__attribute__((address_space(3))) void*)(sA + c * 4096), 16, 0, 0);
      __builtin_amdgcn_global_load_lds(
          (const __attribute__((address_space(1))) void*)(gB + (size_t)c * 32 * rowBytes),
          (__attribute__((address_space(3))) void*)(sB + c * 4096), 16, 0, 0);
    }
    __syncthreads();
#pragma unroll
    for (int kk = 0; kk < 64; kk += 32) {
      bf16x8 af[4], bw[4];
#pragma unroll
      for (int i = 0; i < 4; ++i)
        af[i] = *(const bf16x8*)&lA[(WM + i * 16 + lr) * 64 + kk + kg * 8];
#pragma unroll
      for (int j = 0; j < 4; ++j)
        bw[j] = *(const bf16x8*)&lB[(WN + j * 16 + lr) * 64 + kk + kg * 8];
#pragma unroll
      for (int i = 0; i < 4; ++i)
#pragma unroll
        for (int j = 0; j < 4; ++j)
          acc[i][j] = __builtin_amdgcn_mfma_f32_16x16x32_bf16(af[i], bw[j], acc[i][j], 0, 0, 0);
    }
  }
  float* Cf = (float*)Cp;
  u16* Cb = (u16*)Cp;
#pragma unroll
  for (int i = 0; i < 4; ++i) {
#pragma unroll
    for (int j = 0; j < 4; ++j) {
      const int gc = n0 + WN + j * 16 + lr;
      float bv = 0.f;
      if (HAS_BIAS) bv = b2f(bias[(size_t)z * Bz + gc]);
#pragma unroll
      for (int t = 0; t < 4; ++t) {
        const int gr = m0 + WM + i * 16 + kg * 4 + t;   // C/D: col=lane&15, row=(lane>>4)*4+reg
        const float v = acc[i][j][t] + bv;
        const size_t idx = (size_t)z * Cz + (size_t)gr * ldc + gc;
        if (OUT_BF16) Cb[idx] = f2bf(v); else Cf[idx] = v;
      }
    }
  }
}

// ---------------- exact-dtype fp32 GEMM for the score path ----------------
__global__ __launch_bounds__(256) void gemm_f32bf_kernel(
    const void* __restrict__ A, const void* __restrict__ W, float* __restrict__ C,
    const void* __restrict__ bias, const int* __restrict__ flagp,
    int K, int lda, int ldw, int ldc, long Az, long Wz, long Cz)
{
  const int f32 = flagp[0];
  __shared__ float sA[16][65];
  __shared__ float sW[16][64];
  const int tid = threadIdx.x;
  const int m0 = blockIdx.x * 64, n0 = blockIdx.y * 64, z = blockIdx.z;
  const int tx = tid & 15, ty = tid >> 4;
  const int ar = tid >> 2, ak = (tid & 3) * 4;
  const int wk = tid >> 4, wc = (tid & 15) * 4;
  const size_t abase = (size_t)z * Az, wbase = (size_t)z * Wz;
  float acc[4][4] = {};
  for (int k0 = 0; k0 < K; k0 += 16) {
    __syncthreads();
    float a0, a1, a2, a3, w0, w1, w2, w3;
    const size_t ai = abase + (size_t)(m0 + ar) * lda + k0 + ak;
    const size_t wi = wbase + (size_t)(k0 + wk) * ldw + n0 + wc;
    if (f32) {
      const float4 av = *(const float4*)((const float*)A + ai);
      const float4 wv = *(const float4*)((const float*)W + wi);
      a0 = av.x; a1 = av.y; a2 = av.z; a3 = av.w;
      w0 = wv.x; w1 = wv.y; w2 = wv.z; w3 = wv.w;
    } else {
      const ushort4 av = *(const ushort4*)((const u16*)A + ai);
      const ushort4 wv = *(const ushort4*)((const u16*)W + wi);
      a0 = b2f(av.x); a1 = b2f(av.y); a2 = b2f(av.z); a3 = b2f(av.w);
      w0 = b2f(wv.x); w1 = b2f(wv.y); w2 = b2f(wv.z); w3 = b2f(wv.w);
    }
    sA[ak + 0][ar] = a0; sA[ak + 1][ar] = a1; sA[ak + 2][ar] = a2; sA[ak + 3][ar] = a3;
    sW[wk][wc] = w0; sW[wk][wc + 1] = w1; sW[wk][wc + 2] = w2; sW[wk][wc + 3] = w3;
    __syncthreads();
#pragma unroll
    for (int kk = 0; kk < 16; ++kk) {
      const float a0c = sA[kk][ty * 4 + 0], a1c = sA[kk][ty * 4 + 1];
      const float a2c = sA[kk][ty * 4 + 2], a3c = sA[kk][ty * 4 + 3];
      const float4 bv = *(const float4*)&sW[kk][tx * 4];
      acc[0][0] += a0c * bv.x; acc[0][1] += a0c * bv.y; acc[0][2] += a0c * bv.z; acc[0][3] += a0c * bv.w;
      acc[1][0] += a1c * bv.x; acc[1][1] += a1c * bv.y; acc[1][2] += a1c * bv.z; acc[1][3] += a1c * bv.w;
      acc[2][0] += a2c * bv.x; acc[2][1] += a2c * bv.y; acc[2][2] += a2c * bv.z; acc[2][3] += a2c * bv.w;
      acc[3][0] += a3c * bv.x; acc[3][1] += a3c * bv.y; acc[3][2] += a3c * bv.z; acc[3][3] += a3c * bv.w;
    }
  }
#pragma unroll
  for (int i = 0; i < 4; ++i)
#pragma unroll
    for (int j = 0; j < 4; ++j) {
      const int n = n0 + tx * 4 + j;
      float v = acc[i][j];
      if (bias) v += ldin(bias, n, f32);
      C[(size_t)z * Cz + (size_t)(m0 + ty * 4 + i) * ldc + n] = v;
    }
}

// ---------------- scores / top-k / probs -> mask, inp ----------------
__global__ __launch_bounds__(256) void select_kernel(
    const float* __restrict__ q_l, const float* __restrict__ k_l,
    const void* __restrict__ key_b, const void* __restrict__ value_b,
    const float* __restrict__ v_l, const int* __restrict__ flagp,
    float* __restrict__ mask_out, u16* __restrict__ inp)
{
  const int b = blockIdx.x, tid = threadIdx.x;
  const int f32 = flagp[0];
  __shared__ float s_sc[16], s_pm[8], s_pm1[8];
  __shared__ float s_v[400], s_vb[400];
  const int task = tid >> 4, l16 = tid & 15, uu = task & 7;
  const float* qv = q_l + (size_t)b * 512 + uu * 64;
  float p = 0.f;
  if (task < 8) {
    const float* kv = k_l + (size_t)b * 64;
    for (int k = l16; k < 64; k += 16) p += qv[k] * kv[k];
  } else {
    for (int k = l16; k < 64; k += 16) p += qv[k] * ldin(key_b, k, f32);
  }
  p += __shfl_xor(p, 8, 16); p += __shfl_xor(p, 4, 16);
  p += __shfl_xor(p, 2, 16); p += __shfl_xor(p, 1, 16);
  if (l16 == 0) s_sc[task] = p * 0.125f;
  for (int i = tid; i < 400; i += 256) { s_v[i] = v_l[(size_t)b * 512 + i]; s_vb[i] = ldin(value_b, i, f32); }
  __syncthreads();
  if (tid < 8) {
    const float s0 = s_sc[tid];
    int rank = 0;
    for (int u2 = 0; u2 < 8; ++u2) {
      const float o = s_sc[u2];
      rank += (o > s0) || (o == s0 && u2 < tid);
    }
    const float m = (rank < 5) ? 1.f : 0.f;
    mask_out[(size_t)b * 8 + tid] = m;
    const float s1 = s_sc[8 + tid];
    const float mx = fmaxf(s0, s1);
    const float e0 = expf(s0 - mx), e1 = expf(s1 - mx);
    const float p0 = e0 / (e0 + e1);
    s_pm[tid] = m * p0; s_pm1[tid] = m * (1.f - p0);
  }
  __syncthreads();
#pragma unroll
  for (int u = 0; u < 8; ++u) {
    const float pm = s_pm[u], pm1 = s_pm1[u];
    for (int i = tid; i < 448; i += 256) {
      const float v = (i < 400) ? (pm * s_v[i] + pm1 * s_vb[i]) : 0.f;
      inp[((size_t)u * 4096 + b) * 448 + i] = f2bf(v);
    }
  }
}

// ---------------- shared 2-value block reduction (128 threads) ----------------
__device__ __forceinline__ void block_reduce_2(float& a, float& b) {
#pragma unroll
  for (int o = 32; o; o >>= 1) { a += __shfl_down(a, o, 64); b += __shfl_down(b, o, 64); }
  __shared__ float red[4];
  const int tid = threadIdx.x;
  if ((tid & 63) == 0) { red[(tid >> 6) * 2] = a; red[(tid >> 6) * 2 + 1] = b; }
  __syncthreads();
  a = red[0] + red[2]; b = red[1] + red[3];
}

// ---------------- GRU gates (hmask+b_hh fold) + per-unit LN -> out0, hb ----------------
__global__ __launch_bounds__(128) void gates_kernel(
    const u16* __restrict__ gi, const u16* __restrict__ gh,
    const u16* __restrict__ hsb, const float* __restrict__ hmf,
    const u16* __restrict__ bhh, const u16* __restrict__ rng, const u16* __restrict__ rnb,
    const int* __restrict__ flagp, int bbase, void* __restrict__ out0, u16* __restrict__ hb)
{
  const int f = flagp[0];
  const int bid = blockIdx.x;
  const int u = bid >> 10, bl = bid & 1023;
  const int b = bbase + bl;
  const int h0 = threadIdx.x * 4;
  const size_t rowg = ((size_t)u * 1024 + bl) * 1536;
  const size_t rowh = ((size_t)u * 4096 + b) * 512;
  float ir[4], iz[4], inn[4], hr[4], hz[4], hnn[4], hsv[4], br[4], bz[4], bn[4];
  ld4bf(gi + rowg + h0, ir);
  ld4bf(gi + rowg + 512 + h0, iz);
  ld4bf(gi + rowg + 1024 + h0, inn);
  ld4bf(gh + rowg + h0, hr);
  ld4bf(gh + rowg + 512 + h0, hz);
  ld4bf(gh + rowg + 1024 + h0, hnn);
  ld4bf(hsb + rowh + h0, hsv);
  ld4bf(bhh + u * 1536 + h0, br);
  ld4bf(bhh + u * 1536 + 512 + h0, bz);
  ld4bf(bhh + u * 1536 + 1024 + h0, bn);
  const float hmask = hmf[b];
  float hn[4]; float sum = 0.f, sq = 0.f;
#pragma unroll
  for (int j = 0; j < 4; ++j) {
    const float hrf = hmask * hr[j] + br[j];
    const float hzf = hmask * hz[j] + bz[j];
    const float hnf = hmask * hnn[j] + bn[j];
    const float r = 1.f / (1.f + expf(-(ir[j] + hrf)));
    const float zz = 1.f / (1.f + expf(-(iz[j] + hzf)));
    const float n = tanhf(inn[j] + r * hnf);
    const float hmv = hsv[j] * hmask;
    const float h = (1.f - zz) * n + zz * hmv;
    hn[j] = h; sum += h; sq += h * h;
  }
  block_reduce_2(sum, sq);
  const float mean = sum * (1.f / 512.f);
  const float var = fmaxf(sq * (1.f / 512.f) - mean * mean, 0.f);
  const float rstd = rsqrtf(var + 1e-5f);
  float gg[4], bb[4];
  ld4bf(rng + u * 512 + h0, gg);
  ld4bf(rnb + u * 512 + h0, bb);
  float yv[4];
#pragma unroll
  for (int j = 0; j < 4; ++j) yv[j] = (hn[j] - mean) * rstd * gg[j] + bb[j];
  st4out(out0, (size_t)b * 4096 + u * 512 + h0, yv, f);
  ushort4 hv;
  hv.x = f2bf(hn[0]); hv.y = f2bf(hn[1]); hv.z = f2bf(hn[2]); hv.w = f2bf(hn[3]);
  *(ushort4*)(hb + rowh + h0) = hv;
}

// ---------------- per-b 8x8 inter-unit attention -> ctx ----------------
__global__ __launch_bounds__(256) void attn_kernel(
    const u16* __restrict__ qvc, const float* __restrict__ maskp, int bbase,
    u16* __restrict__ ctx)
{
  const int bl = blockIdx.x, tid = threadIdx.x;
  const int b = bbase + bl;
  __shared__ float s_q[8][128], s_k[8][128];
  __shared__ float s_ap[4][8][8];
  __shared__ float s_v[8][400];
  for (int i = tid; i < 1024; i += 256) {
    const int u = i >> 7, c = i & 127;
    const size_t base = ((size_t)u * 2048 + bl) * 768;
    s_q[u][c] = b2f(qvc[base + c]);
    s_k[u][c] = b2f(qvc[base + 128 + c]);
  }
  for (int i = tid; i < 3200; i += 256) {
    const int u = i / 400, c = i - u * 400;
    s_v[u][c] = b2f(qvc[((size_t)u * 2048 + bl) * 768 + 256 + c]);
  }
  __syncthreads();
  const int n = tid >> 6, uu = (tid >> 3) & 7, vv = tid & 7;
  float a = 0.f;
#pragma unroll
  for (int k = 0; k < 32; ++k) a += s_q[uu][n * 32 + k] * s_k[vv][n * 32 + k];
  a *= 0.17677669529663687f;
  float mx = a;
  for (int o = 4; o; o >>= 1) mx = fmaxf(mx, __shfl_xor(mx, o, 8));
  const float e = expf(a - mx);
  float se = e;
  for (int o = 4; o; o >>= 1) se += __shfl_xor(se, o, 8);
  s_ap[n][uu][vv] = e / se * maskp[(size_t)b * 8 + uu];
  __syncthreads();
  for (int i = tid; i < 3584; i += 256) {
    const int u = i / 448, c = i - u * 448;
    float v = 0.f;
    if (c < 400) {
      const int nn = c / 100;
      const float* ap = s_ap[nn][u];
#pragma unroll
      for (int v2 = 0; v2 < 8; ++v2) v += ap[v2] * s_v[v2][c];
    }
    ctx[((size_t)u * 2048 + bl) * 448 + c] = f2bf(v);
  }
}

// ---------------- final LN + masked blend -> out2 ----------------
__global__ __launch_bounds__(128) void final_kernel(
    const u16* __restrict__ ctx2, const u16* __restrict__ hb, const u16* __restrict__ hsb,
    const float* __restrict__ maskp, const u16* __restrict__ lng, const u16* __restrict__ lnb,
    const int* __restrict__ flagp, int bbase, void* __restrict__ outp)
{
  const int f = flagp[0];
  const int bid = blockIdx.x;
  const int u = bid >> 11, bl = bid & 2047;
  const int b = bbase + bl;
  const int h0 = threadIdx.x * 4;
  const size_t rowc = ((size_t)u * 2048 + bl) * 512;
  const size_t rowh = ((size_t)u * 4096 + b) * 512;
  float cv[4], hbv[4];
  ld4bf(ctx2 + rowc + h0, cv);
  ld4bf(hb + rowh + h0, hbv);
  float v[4] = { cv[0] + hbv[0], cv[1] + hbv[1], cv[2] + hbv[2], cv[3] + hbv[3] };
  float sum = v[0] + v[1] + v[2] + v[3];
  float sq = v[0] * v[0] + v[1] * v[1] + v[2] * v[2] + v[3] * v[3];
  block_reduce_2(sum, sq);
  const float mean = sum * (1.f / 512.f);
  const float var = fmaxf(sq * (1.f / 512.f) - mean * mean, 0.f);
  const float rstd = rsqrtf(var + 1e-5f);
  float gg[4], bb2[4], hsv[4];
  ld4bf(lng + h0, gg); ld4bf(lnb + h0, bb2); ld4bf(hsb + rowh + h0, hsv);
  const float msk = maskp[(size_t)b * 8 + u];
  float ov[4];
#pragma unroll
  for (int j = 0; j < 4; ++j)
    ov[j] = msk * ((v[j] - mean) * rstd * gg[j] + bb2[j]) + (1.f - msk) * hsv[j];
  st4out(outp, (size_t)16777216 + (size_t)(b * 8 + u) * 512 + h0, ov, f);
}

extern "C" void kernel_launch(void* const* d_in, const int* in_sizes, int n_in,
                              void* d_out, int out_size, void* d_ws, size_t ws_size,
                              hipStream_t stream) {
  const void* x       = d_in[0];
  const void* hs      = d_in[1];
  const void* h_masks = d_in[2];
  const void* key_w   = d_in[3];
  const void* key_b   = d_in[4];
  const void* value_w = d_in[5];
  const void* value_b = d_in[6];
  const void* query_w = d_in[7];
  const void* qc_w    = d_in[8];
  const void* kc_w    = d_in[9];
  const void* vc_w    = d_in[10];
  const void* out_w   = d_in[11];
  const void* ln_g    = d_in[12];
  const void* ln_b    = d_in[13];
  const void* W_ih    = d_in[14];
  const void* b_ih    = d_in[15];
  const void* W_hh    = d_in[16];
  const void* b_hh    = d_in[17];
  const void* rnn_g   = d_in[18];
  const void* rnn_b   = d_in[19];

  char* ws = (char*)d_ws;
  int*   FLAG = (int*)(ws + OFF_FLAG);
  u16*   WIH  = (u16*)(ws + OFF_WIH);
  u16*   QVW  = (u16*)(ws + OFF_QVW);
  u16*   OUTW = (u16*)(ws + OFF_OUTW);
  u16*   VALW = (u16*)(ws + OFF_VALW);
  u16*   WHH  = (u16*)(ws + OFF_WHH);
  u16*   VBP  = (u16*)(ws + OFF_VBP);
  u16*   BIH  = (u16*)(ws + OFF_BIH);
  u16*   BHH  = (u16*)(ws + OFF_BHH);
  u16*   RNG  = (u16*)(ws + OFF_RNG);
  u16*   RNB  = (u16*)(ws + OFF_RNB);
  u16*   LNG  = (u16*)(ws + OFF_LNG);
  u16*   LNB  = (u16*)(ws + OFF_LNB);
  float* HMF  = (float*)(ws + OFF_HMF);
  u16*   XB   = (u16*)(ws + OFF_XB);
  u16*   HSB  = (u16*)(ws + OFF_HSB);
  float* KL   = (float*)(ws + OFF_KL);
  float* VL   = (float*)(ws + OFF_VL);
  float* QL   = (float*)(ws + OFF_QL);
  float* MASK = (float*)(ws + OFF_MASK);
  u16*   HB   = (u16*)(ws + OFF_HB);
  u16*   INP  = (u16*)(ws + OFF_INP);
  u16*   GI   = (u16*)(ws + OFF_GI);
  u16*   GH   = (u16*)(ws + OFF_GH);
  u16*   QVC  = (u16*)(ws + OFF_QVC);
  u16*   CTX  = (u16*)(ws + OFF_CTX);
  u16*   CTX2 = (u16*)(ws + OFF_CTX2);

  detect_kernel<<<1, 256, 0, stream>>>((const u16*)hs, FLAG);
  prepconv_kernel<<<140438, 256, 0, stream>>>(
      W_ih, qc_w, kc_w, vc_w, out_w, value_w, value_b, W_hh, b_ih, b_hh,
      rnn_g, rnn_b, ln_g, ln_b, x, hs, h_masks, FLAG,
      WIH, QVW, OUTW, VALW, WHH, VBP, BIH, BHH, RNG, RNB, LNG, LNB, XB, HSB, HMF);
  // v_l = x @ value_w + value_b  (MFMA, f32 out)
  gemm_bt_kernel<0, 1><<<dim3(32, 4, 1), 256, 0, stream>>>(XB, VALW, VL, VBP, 512, 0, 0, 0, 0, 512);
  // score path: exact fp32 (top-k stability)
  gemm_f32bf_kernel<<<dim3(64, 1, 1), 256, 0, stream>>>(x, key_w, KL, key_b, FLAG, 512, 512, 64, 64, 0, 0, 0);
  gemm_f32bf_kernel<<<dim3(64, 1, 8), 256, 0, stream>>>(hs, query_w, QL, nullptr, FLAG, 512, 4096, 64, 512, 512, 32768, 64);
  select_kernel<<<4096, 256, 0, stream>>>(QL, KL, key_b, value_b, VL, FLAG, MASK, INP);
  // GRU (MFMA), chunked over batch (4 x 1024 rows)
  for (int c = 0; c < 4; ++c) {
    gemm_bt_kernel<1, 1><<<dim3(8, 12, 8), 256, 0, stream>>>(
        INP + (size_t)c * 1024 * 448, WIH, GI, BIH, 448, 1835008L, 688128L, 1572864L, 1536, 1536);
    gemm_bt_kernel<1, 0><<<dim3(8, 12, 8), 256, 0, stream>>>(
        HSB + (size_t)c * 1024 * 512, WHH, GH, nullptr, 512, 2097152L, 786432L, 1572864L, 0, 1536);
    gates_kernel<<<8192, 128, 0, stream>>>(GI, GH, HSB, HMF, BHH, RNG, RNB, FLAG, c * 1024, d_out, HB);
  }
  // communication attention (MFMA), chunked over batch (2 x 2048 rows)
  for (int d = 0; d < 2; ++d) {
    gemm_bt_kernel<1, 0><<<dim3(16, 6, 8), 256, 0, stream>>>(
        HB + (size_t)d * 2048 * 512, QVW, QVC, nullptr, 512, 2097152L, 393216L, 1572864L, 0, 768);
    attn_kernel<<<2048, 256, 0, stream>>>(QVC, MASK, d * 2048, CTX);
    gemm_bt_kernel<1, 0><<<dim3(16, 4, 8), 256, 0, stream>>>(
        CTX, OUTW, CTX2, nullptr, 448, 917504L, 229376L, 1048576L, 0, 512);
    final_kernel<<<16384, 128, 0, stream>>>(CTX2, HB, HSB, MASK, LNG, LNB, FLAG, d * 2048, d_out);
  }
  (void)in_sizes; (void)n_in; (void)out_size; (void)ws_size;
}

// Round 6
// 590.837 us; speedup vs baseline: 2.9643x; 1.1910x over previous
//
#include <hip/hip_runtime.h>

typedef __attribute__((ext_vector_type(4))) float f32x4;
typedef __attribute__((ext_vector_type(8))) short bf16x8;
typedef unsigned short u16;

#define DEVINL static __device__ __forceinline__

DEVINL float b2f(u16 u) { union { unsigned int i; float f; } x; x.i = ((unsigned int)u) << 16; return x.f; }
DEVINL u16 f2bf(float f) {
  union { float f; unsigned int i; } x; x.f = f;
  unsigned int r = x.i + 0x7fffu + ((x.i >> 16) & 1u);
  return (u16)(r >> 16);
}
DEVINL float ldin(const void* p, long i, int f) {
  return f ? ((const float*)p)[i] : b2f(((const u16*)p)[i]);
}
DEVINL void ld4bf(const u16* p, float* o) {
  ushort4 v = *(const ushort4*)p;
  o[0] = b2f(v.x); o[1] = b2f(v.y); o[2] = b2f(v.z); o[3] = b2f(v.w);
}
DEVINL void st4out(void* out, size_t idx, const float* v, int f) {
  if (f) {
    float4 t; t.x = v[0]; t.y = v[1]; t.z = v[2]; t.w = v[3];
    *(float4*)((float*)out + idx) = t;
  } else {
    ushort4 t; t.x = f2bf(v[0]); t.y = f2bf(v[1]); t.z = f2bf(v[2]); t.w = f2bf(v[3]);
    *(ushort4*)((u16*)out + idx) = t;
  }
}
DEVINL void cv8(const void* s, long i, int f, u16* d) {
  if (f) {
    const float4 a = *(const float4*)((const float*)s + i);
    const float4 b = *(const float4*)((const float*)s + i + 4);
    ushort4 lo, hi;
    lo.x = f2bf(a.x); lo.y = f2bf(a.y); lo.z = f2bf(a.z); lo.w = f2bf(a.w);
    hi.x = f2bf(b.x); hi.y = f2bf(b.y); hi.z = f2bf(b.z); hi.w = f2bf(b.w);
    *(ushort4*)d = lo; *(ushort4*)(d + 4) = hi;
  } else {
    const ushort4 a = *(const ushort4*)((const u16*)s + i);
    const ushort4 b = *(const ushort4*)((const u16*)s + i + 4);
    *(ushort4*)d = a; *(ushort4*)(d + 4) = b;
  }
}

// ---------------- static workspace layout (bytes) ----------------
static constexpr size_t OFF_FLAG = 0;
static constexpr size_t OFF_WIH  = 1024;        // bf16 [8][1536][448]
static constexpr size_t OFF_QVW  = 11011072;    // bf16 [8][768][512]  (qc|kc|vc-pad)
static constexpr size_t OFF_OUTW = 23593984;    // bf16 [8][512][448]
static constexpr size_t OFF_VALW = 27264000;    // bf16 [512][512]
static constexpr size_t OFF_WHH  = 27788288;    // bf16 [8][1536][512]
static constexpr size_t OFF_VBP  = 40371200;    // bf16 [512]
static constexpr size_t OFF_BIH  = 40372224;    // bf16 [8][1536]
static constexpr size_t OFF_BHH  = 40396800;    // bf16 [8][1536]
static constexpr size_t OFF_RNG  = 40421376;    // bf16 [8][512]
static constexpr size_t OFF_RNB  = 40429568;    // bf16 [8][512]
static constexpr size_t OFF_LNG  = 40437760;    // bf16 [512]
static constexpr size_t OFF_LNB  = 40438784;    // bf16 [512]
static constexpr size_t OFF_HMF  = 40439808;    // f32  [4096]
static constexpr size_t OFF_XB   = 40456192;    // bf16 [4096][512]
static constexpr size_t OFF_HSB  = 44650496;    // bf16 [4096][8][512] (STRAIGHT copy of hs)
static constexpr size_t OFF_KL   = 78204928;    // f32  [4096][64]
static constexpr size_t OFF_VL   = 79253504;    // f32  [4096][512]
static constexpr size_t OFF_QL   = 87642112;    // f32  [4096][512]
static constexpr size_t OFF_MASK = 96030720;    // f32  [4096][8]
static constexpr size_t OFF_HB   = 96161792;    // bf16 [8][4096][512] (u-major)
static constexpr size_t OFF_R    = 129716224;   // reusable region (INP + dynamic GI/GH | QVC/CTX/CTX2)

// ---------------- dtype detect: even-u16 plausibility ----------------
__global__ __launch_bounds__(256) void detect_kernel(const u16* __restrict__ hs_u, int* __restrict__ flag) {
  __shared__ int cnt;
  if (threadIdx.x == 0) cnt = 0;
  __syncthreads();
  int ok = 0;
  for (int i = threadIdx.x; i < 1024; i += 256) {
    const float v = fabsf(b2f(hs_u[2 * i]));
    if (v > 9.094947e-13f && v < 1.0995116e12f) ok++;   // 2^-40 .. 2^40
  }
  atomicAdd(&cnt, ok);
  __syncthreads();
  if (threadIdx.x == 0) flag[0] = (cnt >= 921) ? 0 : 1;  // bf16(0) / fp32(1)
}

// ---------------- vectorized flat convert/pad (8 elems/thread) ----------------
__global__ __launch_bounds__(256) void flatconv_kernel(
    const void* __restrict__ W_ih, const void* __restrict__ W_hh, const void* __restrict__ x,
    const void* __restrict__ hs, const void* __restrict__ value_b, const void* __restrict__ b_ih,
    const void* __restrict__ b_hh, const void* __restrict__ rnn_g, const void* __restrict__ rnn_b,
    const void* __restrict__ ln_g, const void* __restrict__ ln_b, const void* __restrict__ h_masks,
    const int* __restrict__ flagp,
    u16* __restrict__ WIH, u16* __restrict__ WHH, u16* __restrict__ XB, u16* __restrict__ HSB,
    u16* __restrict__ VBP, u16* __restrict__ BIH, u16* __restrict__ BHH,
    u16* __restrict__ RNG, u16* __restrict__ RNB, u16* __restrict__ LNG, u16* __restrict__ LNB,
    float* __restrict__ HMF)
{
  const int f = flagp[0];
  long t = (long)blockIdx.x * 256 + threadIdx.x;
  if (t < 688128L) {                         // WIH [r=u*1536][448], pad k>=400
    const long r = t / 56; const int k = (int)(t - r * 56) * 8;
    u16* d = WIH + r * 448 + k;
    if (k < 400) cv8(W_ih, r * 400 + k, f, d);
    else { ushort4 z{0,0,0,0}; *(ushort4*)d = z; *(ushort4*)(d + 4) = z; }
    return;
  }
  t -= 688128L;
  if (t < 786432L) { cv8(W_hh, t * 8, f, WHH + t * 8); return; }
  t -= 786432L;
  if (t < 262144L) { cv8(x, t * 8, f, XB + t * 8); return; }
  t -= 262144L;
  if (t < 2097152L) { cv8(hs, t * 8, f, HSB + t * 8); return; }
  t -= 2097152L;
  if (t < 512L) { VBP[t] = (t < 400) ? f2bf(ldin(value_b, t, f)) : (u16)0; return; }
  t -= 512L;
  if (t < 12288L) { BIH[t] = f2bf(ldin(b_ih, t, f)); return; }
  t -= 12288L;
  if (t < 12288L) { BHH[t] = f2bf(ldin(b_hh, t, f)); return; }
  t -= 12288L;
  if (t < 4096L) { RNG[t] = f2bf(ldin(rnn_g, t, f)); return; }
  t -= 4096L;
  if (t < 4096L) { RNB[t] = f2bf(ldin(rnn_b, t, f)); return; }
  t -= 4096L;
  if (t < 512L) { LNG[t] = f2bf(ldin(ln_g, t, f)); return; }
  t -= 512L;
  if (t < 512L) { LNB[t] = f2bf(ldin(ln_b, t, f)); return; }
  t -= 512L;
  if (t < 4096L) { HMF[t] = ldin(h_masks, t, f); return; }
}

// ---------------- LDS-tiled transpose: dst[z][n][k](bf16,[*][Kp]) = src[z][k][n], zero-pad ----------------
__global__ __launch_bounds__(256) void transpose_kernel(
    const void* __restrict__ src, const int* __restrict__ flagp, u16* __restrict__ dst,
    int K, int N, int Kp, long srcZ, long dstZ)
{
  const int f = flagp[0];
  __shared__ float t[64][65];
  const int k0 = blockIdx.x * 64, n0 = blockIdx.y * 64, z = blockIdx.z;
  const int tid = threadIdx.x;
  const int lk = tid >> 4;            // 0..15
  const int ln4 = (tid & 15) * 4;     // 0..60
#pragma unroll
  for (int p = 0; p < 4; ++p) {
    const int k = k0 + lk + p * 16;
    float v[4] = {0.f, 0.f, 0.f, 0.f};
    if (k < K) {
      const long base = srcZ * z + (long)k * N + n0 + ln4;
#pragma unroll
      for (int j = 0; j < 4; ++j)
        if (n0 + ln4 + j < N) v[j] = ldin(src, base + j, f);
    }
    t[lk + p * 16][ln4 + 0] = v[0]; t[lk + p * 16][ln4 + 1] = v[1];
    t[lk + p * 16][ln4 + 2] = v[2]; t[lk + p * 16][ln4 + 3] = v[3];
  }
  __syncthreads();
#pragma unroll
  for (int p = 0; p < 4; ++p) {
    const int n = n0 + lk + p * 16;
    ushort4 o;
    o.x = f2bf(t[ln4 + 0][lk + p * 16]);
    o.y = f2bf(t[ln4 + 1][lk + p * 16]);
    o.z = f2bf(t[ln4 + 2][lk + p * 16]);
    o.w = f2bf(t[ln4 + 3][lk + p * 16]);
    *(ushort4*)&dst[dstZ * z + (long)n * Kp + k0 + ln4] = o;
  }
}

// ---------------- bf16 MFMA NT GEMM: C[M][ldc] = A[M][K](ldaE) @ W[N][KP]^T (+bias) ----------------
template<int OUT_BF16, int HAS_BIAS>
__global__ __launch_bounds__(256) void gemm_bt_kernel(
    const u16* __restrict__ A, const u16* __restrict__ W, void* __restrict__ Cp,
    const u16* __restrict__ bias, int KP, int ldaE, long Az, long Wz, long Cz, int Bz, int ldc)
{
  __shared__ u16 lA[128 * 64];
  __shared__ u16 lB[128 * 64];
  const int tid = threadIdx.x;
  const int m0 = blockIdx.x * 128, n0 = blockIdx.y * 128, z = blockIdx.z;
  const u16* Au = A + (size_t)z * Az;
  const u16* Wu = W + (size_t)z * Wz;

  const int l = tid & 63, w = tid >> 6;
  const int WM = (w >> 1) * 64, WN = (w & 1) * 64;
  const int lr = l & 15, kg = l >> 4;

  f32x4 acc[4][4];
#pragma unroll
  for (int i = 0; i < 4; ++i)
#pragma unroll
    for (int j = 0; j < 4; ++j) acc[i][j] = (f32x4){0.f, 0.f, 0.f, 0.f};

  const int rowA = tid >> 3;
  const int cb = (tid & 7) * 16;
  const size_t rowBytesA = (size_t)ldaE * 2;
  const size_t rowBytesW = (size_t)KP * 2;

  for (int k0 = 0; k0 < KP; k0 += 64) {
    __syncthreads();
    const char* gA = (const char*)Au + (size_t)(m0 + rowA) * rowBytesA + (size_t)k0 * 2 + cb;
    const char* gB = (const char*)Wu + (size_t)(n0 + rowA) * rowBytesW + (size_t)k0 * 2 + cb;
    char* sA = (char*)lA + (w << 10);
    char* sB = (char*)lB + (w << 10);
#pragma unroll
    for (int c = 0; c < 4; ++c) {
      __builtin_amdgcn_global_load_lds(
          (const __attribute__((address_space(1))) void*)(gA + (size_t)c * 32 * rowBytesA),
          (__attribute__((address_space(3))) void*)(sA + c * 4096), 16, 0, 0);
      __builtin_amdgcn_global_load_lds(
          (const __attribute__((address_space(1))) void*)(gB + (size_t)c * 32 * rowBytesW),
          (__attribute__((address_space(3))) void*)(sB + c * 4096), 16, 0, 0);
    }
    __syncthreads();
#pragma unroll
    for (int kk = 0; kk < 64; kk += 32) {
      bf16x8 af[4], bw[4];
#pragma unroll
      for (int i = 0; i < 4; ++i)
        af[i] = *(const bf16x8*)&lA[(WM + i * 16 + lr) * 64 + kk + kg * 8];
#pragma unroll
      for (int j = 0; j < 4; ++j)
        bw[j] = *(const bf16x8*)&lB[(WN + j * 16 + lr) * 64 + kk + kg * 8];
#pragma unroll
      for (int i = 0; i < 4; ++i)
#pragma unroll
        for (int j = 0; j < 4; ++j)
          acc[i][j] = __builtin_amdgcn_mfma_f32_16x16x32_bf16(af[i], bw[j], acc[i][j], 0, 0, 0);
    }
  }
  float* Cf = (float*)Cp;
  u16* Cb = (u16*)Cp;
#pragma unroll
  for (int i = 0; i < 4; ++i) {
#pragma unroll
    for (int j = 0; j < 4; ++j) {
      const int gc = n0 + WN + j * 16 + lr;
      float bv = 0.f;
      if (HAS_BIAS) bv = b2f(bias[(size_t)z * Bz + gc]);
#pragma unroll
      for (int t = 0; t < 4; ++t) {
        const int gr = m0 + WM + i * 16 + kg * 4 + t;   // C/D: col=lane&15, row=(lane>>4)*4+reg
        const float v = acc[i][j][t] + bv;
        const size_t idx = (size_t)z * Cz + (size_t)gr * ldc + gc;
        if (OUT_BF16) Cb[idx] = f2bf(v); else Cf[idx] = v;
      }
    }
  }
}

// ---------------- exact-dtype fp32 GEMM for the score path ----------------
__global__ __launch_bounds__(256) void gemm_f32bf_kernel(
    const void* __restrict__ A, const void* __restrict__ W, float* __restrict__ C,
    const void* __restrict__ bias, const int* __restrict__ flagp,
    int K, int lda, int ldw, int ldc, long Az, long Wz, long Cz)
{
  const int f32 = flagp[0];
  __shared__ float sA[16][65];
  __shared__ float sW[16][64];
  const int tid = threadIdx.x;
  const int m0 = blockIdx.x * 64, n0 = blockIdx.y * 64, z = blockIdx.z;
  const int tx = tid & 15, ty = tid >> 4;
  const int ar = tid >> 2, ak = (tid & 3) * 4;
  const int wk = tid >> 4, wc = (tid & 15) * 4;
  const size_t abase = (size_t)z * Az, wbase = (size_t)z * Wz;
  float acc[4][4] = {};
  for (int k0 = 0; k0 < K; k0 += 16) {
    __syncthreads();
    float a0, a1, a2, a3, w0, w1, w2, w3;
    const size_t ai = abase + (size_t)(m0 + ar) * lda + k0 + ak;
    const size_t wi = wbase + (size_t)(k0 + wk) * ldw + n0 + wc;
    if (f32) {
      const float4 av = *(const float4*)((const float*)A + ai);
      const float4 wv = *(const float4*)((const float*)W + wi);
      a0 = av.x; a1 = av.y; a2 = av.z; a3 = av.w;
      w0 = wv.x; w1 = wv.y; w2 = wv.z; w3 = wv.w;
    } else {
      const ushort4 av = *(const ushort4*)((const u16*)A + ai);
      const ushort4 wv = *(const ushort4*)((const u16*)W + wi);
      a0 = b2f(av.x); a1 = b2f(av.y); a2 = b2f(av.z); a3 = b2f(av.w);
      w0 = b2f(wv.x); w1 = b2f(wv.y); w2 = b2f(wv.z); w3 = b2f(wv.w);
    }
    sA[ak + 0][ar] = a0; sA[ak + 1][ar] = a1; sA[ak + 2][ar] = a2; sA[ak + 3][ar] = a3;
    sW[wk][wc] = w0; sW[wk][wc + 1] = w1; sW[wk][wc + 2] = w2; sW[wk][wc + 3] = w3;
    __syncthreads();
#pragma unroll
    for (int kk = 0; kk < 16; ++kk) {
      const float a0c = sA[kk][ty * 4 + 0], a1c = sA[kk][ty * 4 + 1];
      const float a2c = sA[kk][ty * 4 + 2], a3c = sA[kk][ty * 4 + 3];
      const float4 bv = *(const float4*)&sW[kk][tx * 4];
      acc[0][0] += a0c * bv.x; acc[0][1] += a0c * bv.y; acc[0][2] += a0c * bv.z; acc[0][3] += a0c * bv.w;
      acc[1][0] += a1c * bv.x; acc[1][1] += a1c * bv.y; acc[1][2] += a1c * bv.z; acc[1][3] += a1c * bv.w;
      acc[2][0] += a2c * bv.x; acc[2][1] += a2c * bv.y; acc[2][2] += a2c * bv.z; acc[2][3] += a2c * bv.w;
      acc[3][0] += a3c * bv.x; acc[3][1] += a3c * bv.y; acc[3][2] += a3c * bv.z; acc[3][3] += a3c * bv.w;
    }
  }
#pragma unroll
  for (int i = 0; i < 4; ++i)
#pragma unroll
    for (int j = 0; j < 4; ++j) {
      const int n = n0 + tx * 4 + j;
      float v = acc[i][j];
      if (bias) v += ldin(bias, n, f32);
      C[(size_t)z * Cz + (size_t)(m0 + ty * 4 + i) * ldc + n] = v;
    }
}

// ---------------- scores / top-k / probs -> mask, inp ----------------
__global__ __launch_bounds__(256) void select_kernel(
    const float* __restrict__ q_l, const float* __restrict__ k_l,
    const void* __restrict__ key_b, const void* __restrict__ value_b,
    const float* __restrict__ v_l, const int* __restrict__ flagp,
    float* __restrict__ mask_out, u16* __restrict__ inp)
{
  const int b = blockIdx.x, tid = threadIdx.x;
  const int f32 = flagp[0];
  __shared__ float s_sc[16], s_pm[8], s_pm1[8];
  __shared__ float s_v[400], s_vb[400];
  const int task = tid >> 4, l16 = tid & 15, uu = task & 7;
  const float* qv = q_l + (size_t)b * 512 + uu * 64;
  float p = 0.f;
  if (task < 8) {
    const float* kv = k_l + (size_t)b * 64;
    for (int k = l16; k < 64; k += 16) p += qv[k] * kv[k];
  } else {
    for (int k = l16; k < 64; k += 16) p += qv[k] * ldin(key_b, k, f32);
  }
  p += __shfl_xor(p, 8, 16); p += __shfl_xor(p, 4, 16);
  p += __shfl_xor(p, 2, 16); p += __shfl_xor(p, 1, 16);
  if (l16 == 0) s_sc[task] = p * 0.125f;
  for (int i = tid; i < 400; i += 256) { s_v[i] = v_l[(size_t)b * 512 + i]; s_vb[i] = ldin(value_b, i, f32); }
  __syncthreads();
  if (tid < 8) {
    const float s0 = s_sc[tid];
    int rank = 0;
    for (int u2 = 0; u2 < 8; ++u2) {
      const float o = s_sc[u2];
      rank += (o > s0) || (o == s0 && u2 < tid);
    }
    const float m = (rank < 5) ? 1.f : 0.f;
    mask_out[(size_t)b * 8 + tid] = m;
    const float s1 = s_sc[8 + tid];
    const float mx = fmaxf(s0, s1);
    const float e0 = expf(s0 - mx), e1 = expf(s1 - mx);
    const float p0 = e0 / (e0 + e1);
    s_pm[tid] = m * p0; s_pm1[tid] = m * (1.f - p0);
  }
  __syncthreads();
#pragma unroll
  for (int u = 0; u < 8; ++u) {
    const float pm = s_pm[u], pm1 = s_pm1[u];
    for (int i = tid; i < 448; i += 256) {
      const float v = (i < 400) ? (pm * s_v[i] + pm1 * s_vb[i]) : 0.f;
      inp[((size_t)u * 4096 + b) * 448 + i] = f2bf(v);
    }
  }
}

// ---------------- shared 2-value block reduction (128 threads) ----------------
__device__ __forceinline__ void block_reduce_2(float& a, float& b) {
#pragma unroll
  for (int o = 32; o; o >>= 1) { a += __shfl_down(a, o, 64); b += __shfl_down(b, o, 64); }
  __shared__ float red[4];
  const int tid = threadIdx.x;
  if ((tid & 63) == 0) { red[(tid >> 6) * 2] = a; red[(tid >> 6) * 2 + 1] = b; }
  __syncthreads();
  a = red[0] + red[2]; b = red[1] + red[3];
}

// ---------------- GRU gates + per-unit LN -> out0, hb  (grid = [MCG, 8]) ----------------
__global__ __launch_bounds__(128) void gates_kernel(
    const u16* __restrict__ gi, const u16* __restrict__ gh,
    const u16* __restrict__ hsb, const float* __restrict__ hmf,
    const u16* __restrict__ bhh, const u16* __restrict__ rng, const u16* __restrict__ rnb,
    const int* __restrict__ flagp, int bbase, void* __restrict__ out0, u16* __restrict__ hb)
{
  const int f = flagp[0];
  const int u = blockIdx.y, bl = blockIdx.x;
  const int b = bbase + bl;
  const int h0 = threadIdx.x * 4;
  const size_t rowg = ((size_t)u * gridDim.x + bl) * 1536;
  const size_t rowhs = ((size_t)b * 8 + u) * 512;           // HSB b-major
  const size_t rowhb = ((size_t)u * 4096 + b) * 512;        // HB u-major
  float ir[4], iz[4], inn[4], hr[4], hz[4], hnn[4], hsv[4], br[4], bz[4], bn[4];
  ld4bf(gi + rowg + h0, ir);
  ld4bf(gi + rowg + 512 + h0, iz);
  ld4bf(gi + rowg + 1024 + h0, inn);
  ld4bf(gh + rowg + h0, hr);
  ld4bf(gh + rowg + 512 + h0, hz);
  ld4bf(gh + rowg + 1024 + h0, hnn);
  ld4bf(hsb + rowhs + h0, hsv);
  ld4bf(bhh + u * 1536 + h0, br);
  ld4bf(bhh + u * 1536 + 512 + h0, bz);
  ld4bf(bhh + u * 1536 + 1024 + h0, bn);
  const float hmask = hmf[b];
  float hn[4]; float sum = 0.f, sq = 0.f;
#pragma unroll
  for (int j = 0; j < 4; ++j) {
    const float hrf = hmask * hr[j] + br[j];
    const float hzf = hmask * hz[j] + bz[j];
    const float hnf = hmask * hnn[j] + bn[j];
    const float r = 1.f / (1.f + expf(-(ir[j] + hrf)));
    const float zz = 1.f / (1.f + expf(-(iz[j] + hzf)));
    const float n = tanhf(inn[j] + r * hnf);
    const float hmv = hsv[j] * hmask;
    const float h = (1.f - zz) * n + zz * hmv;
    hn[j] = h; sum += h; sq += h * h;
  }
  block_reduce_2(sum, sq);
  const float mean = sum * (1.f / 512.f);
  const float var = fmaxf(sq * (1.f / 512.f) - mean * mean, 0.f);
  const float rstd = rsqrtf(var + 1e-5f);
  float gg[4], bb[4];
  ld4bf(rng + u * 512 + h0, gg);
  ld4bf(rnb + u * 512 + h0, bb);
  float yv[4];
#pragma unroll
  for (int j = 0; j < 4; ++j) yv[j] = (hn[j] - mean) * rstd * gg[j] + bb[j];
  st4out(out0, (size_t)b * 4096 + u * 512 + h0, yv, f);
  ushort4 hv;
  hv.x = f2bf(hn[0]); hv.y = f2bf(hn[1]); hv.z = f2bf(hn[2]); hv.w = f2bf(hn[3]);
  *(ushort4*)(hb + rowhb + h0) = hv;
}

// ---------------- per-b 8x8 inter-unit attention -> ctx (grid = [MCC]) ----------------
__global__ __launch_bounds__(256) void attn_kernel(
    const u16* __restrict__ qvc, const float* __restrict__ maskp, int bbase,
    u16* __restrict__ ctx)
{
  const int bl = blockIdx.x, tid = threadIdx.x;
  const int b = bbase + bl;
  const size_t MC = gridDim.x;
  __shared__ float s_q[8][128], s_k[8][128];
  __shared__ float s_ap[4][8][8];
  __shared__ float s_v[8][400];
  for (int i = tid; i < 1024; i += 256) {
    const int u = i >> 7, c = i & 127;
    const size_t base = ((size_t)u * MC + bl) * 768;
    s_q[u][c] = b2f(qvc[base + c]);
    s_k[u][c] = b2f(qvc[base + 128 + c]);
  }
  for (int i = tid; i < 3200; i += 256) {
    const int u = i / 400, c = i - u * 400;
    s_v[u][c] = b2f(qvc[((size_t)u * MC + bl) * 768 + 256 + c]);
  }
  __syncthreads();
  const int n = tid >> 6, uu = (tid >> 3) & 7, vv = tid & 7;
  float a = 0.f;
#pragma unroll
  for (int k = 0; k < 32; ++k) a += s_q[uu][n * 32 + k] * s_k[vv][n * 32 + k];
  a *= 0.17677669529663687f;   // 1/sqrt(32)
  float mx = a;
  for (int o = 4; o; o >>= 1) mx = fmaxf(mx, __shfl_xor(mx, o, 8));
  const float e = expf(a - mx);
  float se = e;
  for (int o = 4; o; o >>= 1) se += __shfl_xor(se, o, 8);
  s_ap[n][uu][vv] = e / se * maskp[(size_t)b * 8 + uu];
  __syncthreads();
  for (int i = tid; i < 3584; i += 256) {
    const int u = i / 448, c = i - u * 448;
    float v = 0.f;
    if (c < 400) {
      const int nn = c / 100;
      const float* ap = s_ap[nn][u];
#pragma unroll
      for (int v2 = 0; v2 < 8; ++v2) v += ap[v2] * s_v[v2][c];
    }
    ctx[((size_t)u * MC + bl) * 448 + c] = f2bf(v);
  }
}

// ---------------- final LN + masked blend -> out2 (grid = [MCC, 8]) ----------------
__global__ __launch_bounds__(128) void final_kernel(
    const u16* __restrict__ ctx2, const u16* __restrict__ hb, const u16* __restrict__ hsb,
    const float* __restrict__ maskp, const u16* __restrict__ lng, const u16* __restrict__ lnb,
    const int* __restrict__ flagp, int bbase, void* __restrict__ outp)
{
  const int f = flagp[0];
  const int u = blockIdx.y, bl = blockIdx.x;
  const int b = bbase + bl;
  const int h0 = threadIdx.x * 4;
  const size_t rowc = ((size_t)u * gridDim.x + bl) * 512;
  const size_t rowhs = ((size_t)b * 8 + u) * 512;           // HSB b-major
  const size_t rowhb = ((size_t)u * 4096 + b) * 512;        // HB u-major
  float cv[4], hbv[4];
  ld4bf(ctx2 + rowc + h0, cv);
  ld4bf(hb + rowhb + h0, hbv);
  float v[4] = { cv[0] + hbv[0], cv[1] + hbv[1], cv[2] + hbv[2], cv[3] + hbv[3] };
  float sum = v[0] + v[1] + v[2] + v[3];
  float sq = v[0] * v[0] + v[1] * v[1] + v[2] * v[2] + v[3] * v[3];
  block_reduce_2(sum, sq);
  const float mean = sum * (1.f / 512.f);
  const float var = fmaxf(sq * (1.f / 512.f) - mean * mean, 0.f);
  const float rstd = rsqrtf(var + 1e-5f);
  float gg[4], bb2[4], hsv[4];
  ld4bf(lng + h0, gg); ld4bf(lnb + h0, bb2); ld4bf(hsb + rowhs + h0, hsv);
  const float msk = maskp[(size_t)b * 8 + u];
  float ov[4];
#pragma unroll
  for (int j = 0; j < 4; ++j)
    ov[j] = msk * ((v[j] - mean) * rstd * gg[j] + bb2[j]) + (1.f - msk) * hsv[j];
  st4out(outp, (size_t)16777216 + (size_t)(b * 8 + u) * 512 + h0, ov, f);
}

extern "C" void kernel_launch(void* const* d_in, const int* in_sizes, int n_in,
                              void* d_out, int out_size, void* d_ws, size_t ws_size,
                              hipStream_t stream) {
  const void* x       = d_in[0];
  const void* hs      = d_in[1];
  const void* h_masks = d_in[2];
  const void* key_w   = d_in[3];
  const void* key_b   = d_in[4];
  const void* value_w = d_in[5];
  const void* value_b = d_in[6];
  const void* query_w = d_in[7];
  const void* qc_w    = d_in[8];
  const void* kc_w    = d_in[9];
  const void* vc_w    = d_in[10];
  const void* out_w   = d_in[11];
  const void* ln_g    = d_in[12];
  const void* ln_b    = d_in[13];
  const void* W_ih    = d_in[14];
  const void* b_ih    = d_in[15];
  const void* W_hh    = d_in[16];
  const void* b_hh    = d_in[17];
  const void* rnn_g   = d_in[18];
  const void* rnn_b   = d_in[19];

  char* ws = (char*)d_ws;
  int*   FLAG = (int*)(ws + OFF_FLAG);
  u16*   WIH  = (u16*)(ws + OFF_WIH);
  u16*   QVW  = (u16*)(ws + OFF_QVW);
  u16*   OUTW = (u16*)(ws + OFF_OUTW);
  u16*   VALW = (u16*)(ws + OFF_VALW);
  u16*   WHH  = (u16*)(ws + OFF_WHH);
  u16*   VBP  = (u16*)(ws + OFF_VBP);
  u16*   BIH  = (u16*)(ws + OFF_BIH);
  u16*   BHH  = (u16*)(ws + OFF_BHH);
  u16*   RNG  = (u16*)(ws + OFF_RNG);
  u16*   RNB  = (u16*)(ws + OFF_RNB);
  u16*   LNG  = (u16*)(ws + OFF_LNG);
  u16*   LNB  = (u16*)(ws + OFF_LNB);
  float* HMF  = (float*)(ws + OFF_HMF);
  u16*   XB   = (u16*)(ws + OFF_XB);
  u16*   HSB  = (u16*)(ws + OFF_HSB);
  float* KL   = (float*)(ws + OFF_KL);
  float* VL   = (float*)(ws + OFF_VL);
  float* QL   = (float*)(ws + OFF_QL);
  float* MASK = (float*)(ws + OFF_MASK);
  u16*   HB   = (u16*)(ws + OFF_HB);
  u16*   INP  = (u16*)(ws + OFF_R);

  detect_kernel<<<1, 256, 0, stream>>>((const u16*)hs, FLAG);
  flatconv_kernel<<<15126, 256, 0, stream>>>(
      W_ih, W_hh, x, hs, value_b, b_ih, b_hh, rnn_g, rnn_b, ln_g, ln_b, h_masks, FLAG,
      WIH, WHH, XB, HSB, VBP, BIH, BHH, RNG, RNB, LNG, LNB, HMF);
  // weight transposes (dst[n][k] = src[k][n], zero-padded)
  transpose_kernel<<<dim3(8, 2, 8), 256, 0, stream>>>(qc_w,    FLAG, QVW,           512, 128, 512, 65536L,  393216L);
  transpose_kernel<<<dim3(8, 2, 8), 256, 0, stream>>>(kc_w,    FLAG, QVW + 65536,   512, 128, 512, 65536L,  393216L);
  transpose_kernel<<<dim3(8, 8, 8), 256, 0, stream>>>(vc_w,    FLAG, QVW + 131072,  512, 400, 512, 204800L, 393216L);
  transpose_kernel<<<dim3(7, 8, 8), 256, 0, stream>>>(out_w,   FLAG, OUTW,          400, 512, 448, 204800L, 229376L);
  transpose_kernel<<<dim3(8, 8, 1), 256, 0, stream>>>(value_w, FLAG, VALW,          512, 400, 512, 0L,      0L);
  // v_l = x @ value_w + value_b  (MFMA, f32 out)
  gemm_bt_kernel<0, 1><<<dim3(32, 4, 1), 256, 0, stream>>>(XB, VALW, VL, VBP, 512, 512, 0L, 0L, 0L, 0, 512);
  // score path: exact dtype (top-k stability)
  gemm_f32bf_kernel<<<dim3(64, 1, 1), 256, 0, stream>>>(x, key_w, KL, key_b, FLAG, 512, 512, 64, 64, 0L, 0L, 0L);
  gemm_f32bf_kernel<<<dim3(64, 1, 8), 256, 0, stream>>>(hs, query_w, QL, nullptr, FLAG, 512, 4096, 64, 512, 512L, 32768L, 64L);
  select_kernel<<<4096, 256, 0, stream>>>(QL, KL, key_b, value_b, VL, FLAG, MASK, INP);

  // ---- GRU: runtime-adaptive chunking over batch ----
  const size_t base_g = OFF_R + 29360128UL;   // after INP
  int MCG = 4096;
  if (ws_size < base_g + 2UL * 8 * 4096 * 1536 * 2) MCG = 2048;
  if (ws_size < base_g + 2UL * 8 * 2048 * 1536 * 2) MCG = 1024;
  u16* GI = (u16*)(ws + base_g);
  u16* GH = GI + (size_t)8 * MCG * 1536;
  for (int c = 0; c < 4096 / MCG; ++c) {
    gemm_bt_kernel<1, 1><<<dim3(MCG / 128, 12, 8), 256, 0, stream>>>(
        INP + (size_t)c * MCG * 448, WIH, GI, BIH, 448, 448, 1835008L, 688128L, (long)MCG * 1536, 1536, 1536);
    gemm_bt_kernel<1, 0><<<dim3(MCG / 128, 12, 8), 256, 0, stream>>>(
        HSB + (size_t)c * MCG * 4096, WHH, GH, nullptr, 512, 4096, 512L, 786432L, (long)MCG * 1536, 0, 1536);
    gates_kernel<<<dim3(MCG, 8), 128, 0, stream>>>(GI, GH, HSB, HMF, BHH, RNG, RNB, FLAG, c * MCG, d_out, HB);
  }

  // ---- communication attention: runtime-adaptive chunking ----
  int MCC = 4096;
  if (ws_size < OFF_R + (size_t)8 * 4096 * (768 + 448 + 512) * 2) MCC = 2048;
  u16* QVC  = (u16*)(ws + OFF_R);
  u16* CTX  = QVC + (size_t)8 * MCC * 768;
  u16* CTX2 = CTX + (size_t)8 * MCC * 448;
  for (int d2 = 0; d2 < 4096 / MCC; ++d2) {
    gemm_bt_kernel<1, 0><<<dim3(MCC / 128, 6, 8), 256, 0, stream>>>(
        HB + (size_t)d2 * MCC * 512, QVW, QVC, nullptr, 512, 512, 2097152L, 393216L, (long)MCC * 768, 0, 768);
    attn_kernel<<<dim3(MCC), 256, 0, stream>>>(QVC, MASK, d2 * MCC, CTX);
    gemm_bt_kernel<1, 0><<<dim3(MCC / 128, 4, 8), 256, 0, stream>>>(
        CTX, OUTW, CTX2, nullptr, 448, 448, (long)MCC * 448, 229376L, (long)MCC * 512, 0, 512);
    final_kernel<<<dim3(MCC, 8), 128, 0, stream>>>(CTX2, HB, HSB, MASK, LNG, LNB, FLAG, d2 * MCC, d_out);
  }
  (void)in_sizes; (void)n_in; (void)out_size; (void)ws_size;
}